// Round 1
// baseline (810.275 us; speedup 1.0000x reference)
//
#include <hip/hip_runtime.h>

#define BS 256
#define FB 1024         // threads for bucket-parallel phases
#define NB 256          // dst-range buckets (one block each in phases 2/3)
#define CHUNK 4096      // edges per phase-1 block
#define CAP 64          // slots per (chunk,bucket); Poisson(16), +12 sigma
#define LCAP 8192       // entries per bucket in LDS; Poisson(6250), +24 sigma

using half4 = __attribute__((ext_vector_type(4))) _Float16;

template<typename T>
__device__ __forceinline__ float4 load4(const T* p) {
    if constexpr (sizeof(T) == 4) {
        return *(const float4*)p;
    } else {
        half4 v = *(const half4*)p;
        return make_float4((float)v.x, (float)v.y, (float)v.z, (float)v.w);
    }
}
template<typename T>
__device__ __forceinline__ void store4(T* p, float4 v) {
    if constexpr (sizeof(T) == 4) {
        *(float4*)p = v;
    } else {
        half4 h = {(_Float16)v.x, (_Float16)v.y, (_Float16)v.z, (_Float16)v.w};
        *(half4*)p = h;
    }
}

// ---------------- CSR build ----------------

__global__ __launch_bounds__(BS) void k_zero1(int* a, int n) {
    int i = blockIdx.x * BS + threadIdx.x;
    if (i < n) a[i] = 0;
}

// Phase 1: bucket edges into block-private regions (packed doff<<17|src).
// No global atomics; writes are block-exclusive and slot-0-packed (dense).
__global__ __launch_bounds__(BS) void k_bucket(const int* __restrict__ src, const int* __restrict__ dst,
                                               unsigned* __restrict__ bbuf, int* __restrict__ bcounts,
                                               int E, unsigned long long invB, int bsz) {
    __shared__ int lcnt[NB];
    for (int t = threadIdx.x; t < NB; t += BS) lcnt[t] = 0;
    __syncthreads();
    int base_e = blockIdx.x * CHUNK;
    unsigned* mybuf = bbuf + (size_t)blockIdx.x * NB * CAP;
    #pragma unroll
    for (int j = 0; j < CHUNK / BS; ++j) {
        int e = base_e + j * BS + threadIdx.x;
        if (e < E) {
            int d = dst[e];
            int s = src[e];
            int b = (int)(((unsigned long long)(unsigned)d * invB) >> 40);
            int doff = d - b * bsz;                       // < 512 (9 bits)
            int pos = atomicAdd(&lcnt[b], 1);
            if (pos < CAP)                                // overflow ~impossible (+12 sigma)
                mybuf[b * CAP + pos] = ((unsigned)doff << 17) | (unsigned)s;
        }
    }
    __syncthreads();
    for (int t = threadIdx.x; t < NB; t += BS)
        bcounts[blockIdx.x * NB + t] = min(lcnt[t], CAP);
}

// Phase 2: per-bucket degree counts. Slot-parallel: each thread strides over
// nch*CAP slots (seg = idx>>6 wave-uniform), fully independent loads.
__global__ __launch_bounds__(FB) void k_cnt(const unsigned* __restrict__ bbuf, const int* __restrict__ bcounts,
                                            int* __restrict__ cnt, int nch, int bsz, int N) {
    __shared__ int lhist[512];
    for (int t = threadIdx.x; t < 512; t += FB) lhist[t] = 0;
    __syncthreads();
    int b = blockIdx.x;
    int lo = b * bsz;
    int total = nch * CAP;
    for (int idx = threadIdx.x; idx < total; idx += FB) {
        int seg = idx >> 6, slot = idx & 63;              // CAP == 64
        int c = bcounts[seg * NB + b];                    // wave-uniform
        if (slot < c)
            atomicAdd(&lhist[bbuf[((size_t)seg * NB + b) * CAP + slot] >> 17], 1);
    }
    __syncthreads();
    int hi = min(N, lo + bsz);
    for (int t = threadIdx.x; t < hi - lo; t += FB) cnt[lo + t] = lhist[t];
}

__global__ __launch_bounds__(BS) void k_dinv(const int* __restrict__ cnt, float* __restrict__ dinv, int N) {
    int i = blockIdx.x * BS + threadIdx.x;
    if (i < N) dinv[i] = rsqrtf((float)(cnt[i] + 1));   // +1 = self-loop
}

__global__ __launch_bounds__(BS) void k_scan1(const int* __restrict__ cnt, int* __restrict__ bsum, int N) {
    __shared__ int s[BS];
    int i = blockIdx.x * BS + threadIdx.x;
    s[threadIdx.x] = (i < N) ? cnt[i] : 0;
    __syncthreads();
    for (int off = BS / 2; off > 0; off >>= 1) {
        if (threadIdx.x < off) s[threadIdx.x] += s[threadIdx.x + off];
        __syncthreads();
    }
    if (threadIdx.x == 0) bsum[blockIdx.x] = s[0];
}

__global__ __launch_bounds__(512) void k_scan2(int* bsum, int nb) {
    __shared__ int s[512];
    int t = threadIdx.x;
    int v = (t < nb) ? bsum[t] : 0;
    s[t] = v;
    __syncthreads();
    for (int off = 1; off < 512; off <<= 1) {
        int u = (t >= off) ? s[t - off] : 0;
        __syncthreads();
        s[t] += u;
        __syncthreads();
    }
    if (t < nb) bsum[t] = s[t] - v;   // exclusive of self
}

__global__ __launch_bounds__(BS) void k_scan3(const int* __restrict__ cnt, const int* __restrict__ boff,
                                              int* __restrict__ row_ptr, int N) {
    __shared__ int s[BS];
    int t = threadIdx.x;
    int i = blockIdx.x * BS + t;
    int v = (i < N) ? cnt[i] : 0;
    s[t] = v;
    __syncthreads();
    for (int off = 1; off < BS; off <<= 1) {
        int u = (t >= off) ? s[t - off] : 0;
        __syncthreads();
        s[t] += u;
        __syncthreads();
    }
    int base = boff[blockIdx.x];
    if (i < N) row_ptr[i] = base + s[t] - v;
    if (i == N - 1) row_ptr[N] = base + s[t];
}

// Phase 3: slot-parallel counting-sort straight into LDS (no staging pass),
// then stream sorted entries to global with sequential coalesced stores.
__global__ __launch_bounds__(FB) void k_fill2(const unsigned* __restrict__ bbuf, const int* __restrict__ bcounts,
                                              const int* __restrict__ row_ptr, const float* __restrict__ dinv,
                                              uint2* __restrict__ entries,
                                              int nch, int bsz, int N) {
    __shared__ int cur[512];
    __shared__ float ldinv[512];
    __shared__ unsigned sorted[LCAP];

    int b = blockIdx.x;
    int lo = b * bsz;
    int hi = min(N, lo + bsz);
    int gbase = row_ptr[lo];
    int tot = row_ptr[hi] - gbase;
    for (int t = threadIdx.x; t < hi - lo; t += FB) {
        cur[t] = row_ptr[lo + t] - gbase;
        ldinv[t] = dinv[lo + t];
    }
    __syncthreads();

    // Merged gather + counting-sort: independent loads, deep pipelining.
    int total = nch * CAP;
    for (int idx = threadIdx.x; idx < total; idx += FB) {
        int seg = idx >> 6, slot = idx & 63;              // CAP == 64
        int c = bcounts[seg * NB + b];                    // wave-uniform
        if (slot < c) {
            unsigned u = bbuf[((size_t)seg * NB + b) * CAP + slot];
            int p = atomicAdd(&cur[u >> 17], 1);
            if (p < LCAP) sorted[p] = u;
        }
    }
    __syncthreads();

    // Sequential write-out; entries[gbase+t] is d-sorted by construction.
    for (int t = threadIdx.x; t < tot; t += FB) {
        unsigned u = sorted[t];
        int s = (int)(u & 0x1FFFFu);
        int doff = (int)(u >> 17);
        float w = dinv[s] * ldinv[doff];
        entries[gbase + t] = make_uint2((unsigned)s, __float_as_uint(w));
    }
}

// ---------------- dense transform ----------------
// out[N, LDOUT] = H[N, LDIN] @ W[K, M] (+bias)(+relu).
// Decomposition: one thread per (row-pair, 4-col group). vs the old
// one-thread-per-row version this gives ~8.7x more waves (13/SIMD instead of
// 1.5/SIMD -> latency actually hidden), and cuts LDS broadcast reads per
// thread from K*M4/4 to K. H-row re-reads across the CG column threads hit
// the same L1 lines (adjacent lanes), so HBM traffic is unchanged.
__device__ __forceinline__ void fma4(float4& a, float s, float4 w) {
    a.x = fmaf(s, w.x, a.x); a.y = fmaf(s, w.y, a.y);
    a.z = fmaf(s, w.z, a.z); a.w = fmaf(s, w.w, a.w);
}

template<typename TIN, int K, int M, int LDIN, int LDOUT, bool BIAS, bool RELU, typename TOUT>
__global__ __launch_bounds__(BS) void k_gemm(const TIN* __restrict__ H, const float* __restrict__ Wg,
                                             const float* __restrict__ bias, TOUT* __restrict__ out, int N) {
    constexpr int M4 = (M + 3) & ~3;
    constexpr int CG = M4 / 4;
    __shared__ float Wl[K * M4];
    for (int idx = threadIdx.x; idx < K * M4; idx += BS) {
        int k = idx / M4, m = idx - k * M4;
        Wl[idx] = (m < M) ? Wg[(size_t)k * M + m] : 0.f;
    }
    __syncthreads();

    int nrb = (N + 1) >> 1;                     // row-pairs
    int idx = blockIdx.x * BS + threadIdx.x;
    if (idx >= nrb * CG) return;
    int rb = idx / CG;                          // const divisor -> magic mul
    int cg = idx - rb * CG;
    int c0 = cg * 4;
    int r0 = rb * 2;
    bool two = (r0 + 1 < N);
    int r1 = two ? r0 + 1 : r0;
    const TIN* h0 = H + (size_t)r0 * LDIN;
    const TIN* h1 = H + (size_t)r1 * LDIN;

    float4 a0 = make_float4(0.f, 0.f, 0.f, 0.f);
    float4 a1 = make_float4(0.f, 0.f, 0.f, 0.f);

    constexpr int K4 = K & ~3;
    #pragma unroll
    for (int k = 0; k < K4; k += 4) {
        float4 p = load4(h0 + k);
        float4 q = load4(h1 + k);
        const float* wl = &Wl[k * M4 + c0];
        float4 w0 = *(const float4*)(wl);
        float4 w1 = *(const float4*)(wl + M4);
        float4 w2 = *(const float4*)(wl + 2 * M4);
        float4 w3 = *(const float4*)(wl + 3 * M4);
        fma4(a0, p.x, w0); fma4(a1, q.x, w0);
        fma4(a0, p.y, w1); fma4(a1, q.y, w1);
        fma4(a0, p.z, w2); fma4(a1, q.z, w2);
        fma4(a0, p.w, w3); fma4(a1, q.w, w3);
    }
    #pragma unroll
    for (int k = K4; k < K; ++k) {
        float p = (float)h0[k];
        float q = (float)h1[k];
        float4 w = *(const float4*)&Wl[k * M4 + c0];
        fma4(a0, p, w); fma4(a1, q, w);
    }

    // epilogue: bias/relu; zero-fill cols in [M, M4) (consumers read them).
    float* p0 = &a0.x;
    float* p1 = &a1.x;
    #pragma unroll
    for (int j = 0; j < 4; ++j) {
        int c = c0 + j;
        bool in = (c < M);
        float bb = (BIAS && in) ? bias[c] : 0.f;
        float v0 = in ? p0[j] + bb : 0.f;
        float v1 = in ? p1[j] + bb : 0.f;
        if (RELU) { v0 = fmaxf(v0, 0.f); v1 = fmaxf(v1, 0.f); }
        p0[j] = v0; p1[j] = v1;
    }
    store4(out + (size_t)r0 * LDOUT + c0, a0);
    if (two) store4(out + (size_t)r1 * LDOUT + c0, a1);
}

// ---------------- normalized aggregation ----------------
// out[i,:] = dinv_i^2*T[i,:] + sum_e w_e * T[src_e,:]  (+bias)(+relu)
template<typename TIN, typename TOUT, int M, int M4, int LDI, int LDO, bool BIAS, bool RELU>
__global__ __launch_bounds__(BS) void k_agg(const TIN* __restrict__ T, TOUT* __restrict__ out,
                                            const int* __restrict__ row_ptr, const uint2* __restrict__ entries,
                                            const float* __restrict__ dinv, const float* __restrict__ bias,
                                            int N) {
    constexpr int CG = M4 / 4;
    int idx = blockIdx.x * BS + threadIdx.x;
    if (idx >= N * CG) return;
    int i  = idx / CG;                // const divisor -> magic mul
    int cg = idx - i * CG;
    int c0 = cg * 4;

    float di = dinv[i];
    float4 t0 = load4(T + (size_t)i * LDI + c0);
    float w0 = di * di;
    float4 acc0 = make_float4(w0 * t0.x, w0 * t0.y, w0 * t0.z, w0 * t0.w);
    float4 acc1 = make_float4(0.f, 0.f, 0.f, 0.f);

    int e0 = row_ptr[i], e1 = row_ptr[i + 1];
    int e = e0;
    for (; e + 3 < e1; e += 4) {
        uint2 ea = entries[e];
        uint2 eb = entries[e + 1];
        uint2 ec = entries[e + 2];
        uint2 ed = entries[e + 3];
        float4 ta = load4(T + (size_t)ea.x * LDI + c0);
        float4 tb = load4(T + (size_t)eb.x * LDI + c0);
        float4 tc = load4(T + (size_t)ec.x * LDI + c0);
        float4 td = load4(T + (size_t)ed.x * LDI + c0);
        float wa = __uint_as_float(ea.y), wb = __uint_as_float(eb.y);
        float wc = __uint_as_float(ec.y), wd = __uint_as_float(ed.y);
        acc0.x = fmaf(wa, ta.x, acc0.x); acc0.y = fmaf(wa, ta.y, acc0.y);
        acc0.z = fmaf(wa, ta.z, acc0.z); acc0.w = fmaf(wa, ta.w, acc0.w);
        acc1.x = fmaf(wb, tb.x, acc1.x); acc1.y = fmaf(wb, tb.y, acc1.y);
        acc1.z = fmaf(wb, tb.z, acc1.z); acc1.w = fmaf(wb, tb.w, acc1.w);
        acc0.x = fmaf(wc, tc.x, acc0.x); acc0.y = fmaf(wc, tc.y, acc0.y);
        acc0.z = fmaf(wc, tc.z, acc0.z); acc0.w = fmaf(wc, tc.w, acc0.w);
        acc1.x = fmaf(wd, td.x, acc1.x); acc1.y = fmaf(wd, td.y, acc1.y);
        acc1.z = fmaf(wd, td.z, acc1.z); acc1.w = fmaf(wd, td.w, acc1.w);
    }
    for (; e < e1; ++e) {
        uint2 ea = entries[e];
        float4 ta = load4(T + (size_t)ea.x * LDI + c0);
        float wa = __uint_as_float(ea.y);
        acc0.x = fmaf(wa, ta.x, acc0.x); acc0.y = fmaf(wa, ta.y, acc0.y);
        acc0.z = fmaf(wa, ta.z, acc0.z); acc0.w = fmaf(wa, ta.w, acc0.w);
    }
    acc0.x += acc1.x; acc0.y += acc1.y; acc0.z += acc1.z; acc0.w += acc1.w;

    float* vp = &acc0.x;
    #pragma unroll
    for (int j = 0; j < 4; ++j) {
        if (BIAS && (c0 + j) < M) vp[j] += bias[c0 + j];
        if (RELU) vp[j] = fmaxf(vp[j], 0.f);
    }
    store4(out + (size_t)i * LDO + c0, acc0);
}

// ---------------- driver ----------------

extern "C" void kernel_launch(void* const* d_in, const int* in_sizes, int n_in,
                              void* d_out, int out_size, void* d_ws, size_t ws_size,
                              hipStream_t stream) {
    const float* x  = (const float*)d_in[0];
    const float* W1 = (const float*)d_in[1];
    const float* b1 = (const float*)d_in[2];
    const float* W2 = (const float*)d_in[3];
    const float* b2 = (const float*)d_in[4];
    const float* W3 = (const float*)d_in[5];
    const float* b3 = (const float*)d_in[6];
    const float* W4 = (const float*)d_in[7];
    const float* b4 = (const float*)d_in[8];
    const int* edge_index = (const int*)d_in[9];

    const int N = in_sizes[0] / 88;
    const int E = in_sizes[9] / 2;
    const int* src = edge_index;
    const int* dst = edge_index + E;

    const int nch = (E + CHUNK - 1) / CHUNK;            // 391
    const int bsz = (N + NB - 1) / NB;                  // 391 (< 512, 9-bit doff)
    const unsigned long long invB = ((1ull << 40) + bsz - 1) / bsz;

    char* p = (char*)d_ws;
    auto carve = [&](size_t bytes) { void* r = p; p += (bytes + 255) & ~(size_t)255; return r; };
    int*   cnt     = (int*)  carve((size_t)N * 4);
    float* dinv    = (float*)carve((size_t)N * 4);
    int*   row_ptr = (int*)  carve((size_t)(N + 1) * 4);
    int*   bsum    = (int*)  carve(4096);
    int*   bcounts = (int*)  carve((size_t)nch * NB * 4);
    unsigned* bbuf = (unsigned*)carve((size_t)nch * NB * CAP * 4);
    uint2* entries = (uint2*)carve((size_t)E * 8);
    _Float16* hA   = (_Float16*)carve((size_t)N * 68 * 2);
    _Float16* hB   = (_Float16*)carve((size_t)N * 68 * 2);
    _Float16* hC   = (_Float16*)carve((size_t)N * 68 * 2);

    int gN = (N + BS - 1) / BS;

    k_zero1 <<<gN, BS, 0, stream>>>(cnt, N);
    k_bucket<<<nch, BS, 0, stream>>>(src, dst, bbuf, bcounts, E, invB, bsz);
    k_cnt   <<<NB, FB, 0, stream>>>(bbuf, bcounts, cnt, nch, bsz, N);
    k_dinv  <<<gN, BS, 0, stream>>>(cnt, dinv, N);
    k_scan1 <<<gN, BS, 0, stream>>>(cnt, bsum, N);
    k_scan2 <<<1, 512, 0, stream>>>(bsum, gN);
    k_scan3 <<<gN, BS, 0, stream>>>(cnt, bsum, row_ptr, N);
    k_fill2 <<<NB, FB, 0, stream>>>(bbuf, bcounts, row_ptr, dinv, entries, nch, bsz, N);

    auto agg_grid  = [&](int CG) { return (N * CG + BS - 1) / BS; };
    auto gemm_grid = [&](int M)  { int M4 = (M + 3) & ~3; int CG = M4 / 4;
                                   return (((N + 1) / 2) * CG + BS - 1) / BS; };

    // G1: x(f32,88) @ W1 -> hA(f16, ld68)
    k_gemm<float, 88, 65, 88, 68, false, false, _Float16><<<gemm_grid(65), BS, 0, stream>>>(x, W1, nullptr, hA, N);
    // A1: agg(hA) +b1 +relu -> hB(f16, ld68)
    k_agg<_Float16, _Float16, 65, 68, 68, 68, true, true><<<agg_grid(17), BS, 0, stream>>>(hA, hB, row_ptr, entries, dinv, b1, N);
    // G2: hB @ W2 -> hC(f16, ld64: 128B rows -> exact 2-line gathers)
    k_gemm<_Float16, 65, 50, 68, 64, false, false, _Float16><<<gemm_grid(50), BS, 0, stream>>>(hB, W2, nullptr, hC, N);
    // A2: agg(hC) +b2 -> hA(f16, ld64)
    k_agg<_Float16, _Float16, 50, 52, 64, 64, true, false><<<agg_grid(13), BS, 0, stream>>>(hC, hA, row_ptr, entries, dinv, b2, N);
    // A3: agg(hA) -> hB(f16, ld52)
    k_agg<_Float16, _Float16, 50, 52, 64, 52, false, false><<<agg_grid(13), BS, 0, stream>>>(hA, hB, row_ptr, entries, dinv, nullptr, N);
    // G3: hB @ W3 +b3 +relu -> hC(f16, ld68)
    k_gemm<_Float16, 50, 65, 52, 68, true, true, _Float16><<<gemm_grid(65), BS, 0, stream>>>(hB, W3, b3, hC, N);
    // A4: agg(hC) -> hA(f16, ld68)
    k_agg<_Float16, _Float16, 65, 68, 68, 68, false, false><<<agg_grid(17), BS, 0, stream>>>(hC, hA, row_ptr, entries, dinv, nullptr, N);
    // G4: hA @ W4 +b4 -> d_out(f32, ld88)
    k_gemm<_Float16, 65, 88, 68, 88, true, false, float><<<gemm_grid(88), BS, 0, stream>>>(hA, W4, b4, (float*)d_out, N);
}

// Round 2
// 461.171 us; speedup vs baseline: 1.7570x; 1.7570x over previous
//
#include <hip/hip_runtime.h>

#define BS 256
#define FB 1024         // threads for bucket-parallel phases
#define NB 256          // dst-range buckets (one block each in phases 2/3)
#define CHUNK 4096      // edges per phase-1 block
#define CAP 64          // slots per (chunk,bucket); Poisson(16), +12 sigma
#define LCAP 8192       // entries per bucket in LDS; Poisson(6250), +24 sigma

using half4 = __attribute__((ext_vector_type(4))) _Float16;

template<typename T>
__device__ __forceinline__ float4 load4(const T* p) {
    if constexpr (sizeof(T) == 4) {
        return *(const float4*)p;
    } else {
        half4 v = *(const half4*)p;
        return make_float4((float)v.x, (float)v.y, (float)v.z, (float)v.w);
    }
}
template<typename T>
__device__ __forceinline__ void store4(T* p, float4 v) {
    if constexpr (sizeof(T) == 4) {
        *(float4*)p = v;
    } else {
        half4 h = {(_Float16)v.x, (_Float16)v.y, (_Float16)v.z, (_Float16)v.w};
        *(half4*)p = h;
    }
}

// ---------------- CSR build ----------------

__global__ __launch_bounds__(BS) void k_zero1(int* a, int n) {
    int i = blockIdx.x * BS + threadIdx.x;
    if (i < n) a[i] = 0;
}

// Phase 1: bucket edges into block-private regions (packed doff<<17|src).
// No global atomics; writes are block-exclusive and slot-0-packed (dense).
__global__ __launch_bounds__(BS) void k_bucket(const int* __restrict__ src, const int* __restrict__ dst,
                                               unsigned* __restrict__ bbuf, int* __restrict__ bcounts,
                                               int E, unsigned long long invB, int bsz) {
    __shared__ int lcnt[NB];
    for (int t = threadIdx.x; t < NB; t += BS) lcnt[t] = 0;
    __syncthreads();
    int base_e = blockIdx.x * CHUNK;
    unsigned* mybuf = bbuf + (size_t)blockIdx.x * NB * CAP;
    #pragma unroll
    for (int j = 0; j < CHUNK / BS; ++j) {
        int e = base_e + j * BS + threadIdx.x;
        if (e < E) {
            int d = dst[e];
            int s = src[e];
            int b = (int)(((unsigned long long)(unsigned)d * invB) >> 40);
            int doff = d - b * bsz;                       // < 512 (9 bits)
            int pos = atomicAdd(&lcnt[b], 1);
            if (pos < CAP)                                // overflow ~impossible (+12 sigma)
                mybuf[b * CAP + pos] = ((unsigned)doff << 17) | (unsigned)s;
        }
    }
    __syncthreads();
    for (int t = threadIdx.x; t < NB; t += BS)
        bcounts[blockIdx.x * NB + t] = min(lcnt[t], CAP);
}

// Phase 2: per-bucket degree counts. Slot-parallel: each thread strides over
// nch*CAP slots (seg = idx>>6 wave-uniform), fully independent loads.
__global__ __launch_bounds__(FB) void k_cnt(const unsigned* __restrict__ bbuf, const int* __restrict__ bcounts,
                                            int* __restrict__ cnt, int nch, int bsz, int N) {
    __shared__ int lhist[512];
    for (int t = threadIdx.x; t < 512; t += FB) lhist[t] = 0;
    __syncthreads();
    int b = blockIdx.x;
    int lo = b * bsz;
    int total = nch * CAP;
    for (int idx = threadIdx.x; idx < total; idx += FB) {
        int seg = idx >> 6, slot = idx & 63;              // CAP == 64
        int c = bcounts[seg * NB + b];                    // wave-uniform
        if (slot < c)
            atomicAdd(&lhist[bbuf[((size_t)seg * NB + b) * CAP + slot] >> 17], 1);
    }
    __syncthreads();
    int hi = min(N, lo + bsz);
    for (int t = threadIdx.x; t < hi - lo; t += FB) cnt[lo + t] = lhist[t];
}

__global__ __launch_bounds__(BS) void k_dinv(const int* __restrict__ cnt, float* __restrict__ dinv, int N) {
    int i = blockIdx.x * BS + threadIdx.x;
    if (i < N) dinv[i] = rsqrtf((float)(cnt[i] + 1));   // +1 = self-loop
}

__global__ __launch_bounds__(BS) void k_scan1(const int* __restrict__ cnt, int* __restrict__ bsum, int N) {
    __shared__ int s[BS];
    int i = blockIdx.x * BS + threadIdx.x;
    s[threadIdx.x] = (i < N) ? cnt[i] : 0;
    __syncthreads();
    for (int off = BS / 2; off > 0; off >>= 1) {
        if (threadIdx.x < off) s[threadIdx.x] += s[threadIdx.x + off];
        __syncthreads();
    }
    if (threadIdx.x == 0) bsum[blockIdx.x] = s[0];
}

__global__ __launch_bounds__(512) void k_scan2(int* bsum, int nb) {
    __shared__ int s[512];
    int t = threadIdx.x;
    int v = (t < nb) ? bsum[t] : 0;
    s[t] = v;
    __syncthreads();
    for (int off = 1; off < 512; off <<= 1) {
        int u = (t >= off) ? s[t - off] : 0;
        __syncthreads();
        s[t] += u;
        __syncthreads();
    }
    if (t < nb) bsum[t] = s[t] - v;   // exclusive of self
}

__global__ __launch_bounds__(BS) void k_scan3(const int* __restrict__ cnt, const int* __restrict__ boff,
                                              int* __restrict__ row_ptr, int N) {
    __shared__ int s[BS];
    int t = threadIdx.x;
    int i = blockIdx.x * BS + t;
    int v = (i < N) ? cnt[i] : 0;
    s[t] = v;
    __syncthreads();
    for (int off = 1; off < BS; off <<= 1) {
        int u = (t >= off) ? s[t - off] : 0;
        __syncthreads();
        s[t] += u;
        __syncthreads();
    }
    int base = boff[blockIdx.x];
    if (i < N) row_ptr[i] = base + s[t] - v;
    if (i == N - 1) row_ptr[N] = base + s[t];
}

// Phase 3: slot-parallel counting-sort straight into LDS (no staging pass),
// then stream sorted entries to global with sequential coalesced stores.
__global__ __launch_bounds__(FB) void k_fill2(const unsigned* __restrict__ bbuf, const int* __restrict__ bcounts,
                                              const int* __restrict__ row_ptr, const float* __restrict__ dinv,
                                              uint2* __restrict__ entries,
                                              int nch, int bsz, int N) {
    __shared__ int cur[512];
    __shared__ float ldinv[512];
    __shared__ unsigned sorted[LCAP];

    int b = blockIdx.x;
    int lo = b * bsz;
    int hi = min(N, lo + bsz);
    int gbase = row_ptr[lo];
    int tot = row_ptr[hi] - gbase;
    for (int t = threadIdx.x; t < hi - lo; t += FB) {
        cur[t] = row_ptr[lo + t] - gbase;
        ldinv[t] = dinv[lo + t];
    }
    __syncthreads();

    // Merged gather + counting-sort: independent loads, deep pipelining.
    int total = nch * CAP;
    for (int idx = threadIdx.x; idx < total; idx += FB) {
        int seg = idx >> 6, slot = idx & 63;              // CAP == 64
        int c = bcounts[seg * NB + b];                    // wave-uniform
        if (slot < c) {
            unsigned u = bbuf[((size_t)seg * NB + b) * CAP + slot];
            int p = atomicAdd(&cur[u >> 17], 1);
            if (p < LCAP) sorted[p] = u;
        }
    }
    __syncthreads();

    // Sequential write-out; entries[gbase+t] is d-sorted by construction.
    for (int t = threadIdx.x; t < tot; t += FB) {
        unsigned u = sorted[t];
        int s = (int)(u & 0x1FFFFu);
        int doff = (int)(u >> 17);
        float w = dinv[s] * ldinv[doff];
        entries[gbase + t] = make_uint2((unsigned)s, __float_as_uint(w));
    }
}

// ---------------- dense transform ----------------
// out[N, LDOUT] = H[N, LDIN] @ W[K, M] (+bias)(+relu).
// Decomposition: one thread per (row-pair, 4-col group) -> ~6-13 waves/SIMD
// (vs 1.5 for one-thread-per-row), so global/LDS latency is actually hidden.
// k-loop unroll is capped at 2: full unroll hoists all row loads (44 float4
// for K=88) past the 256-VGPR cap -> scratch spill (measured: 356 MB
// WRITE_SIZE, 26x output, 265 us). unroll 2 keeps ~80 VGPRs live, no spill.
__device__ __forceinline__ void fma4(float4& a, float s, float4 w) {
    a.x = fmaf(s, w.x, a.x); a.y = fmaf(s, w.y, a.y);
    a.z = fmaf(s, w.z, a.z); a.w = fmaf(s, w.w, a.w);
}

template<typename TIN, int K, int M, int LDIN, int LDOUT, bool BIAS, bool RELU, typename TOUT>
__global__ __launch_bounds__(BS) void k_gemm(const TIN* __restrict__ H, const float* __restrict__ Wg,
                                             const float* __restrict__ bias, TOUT* __restrict__ out, int N) {
    constexpr int M4 = (M + 3) & ~3;
    constexpr int CG = M4 / 4;
    __shared__ float Wl[K * M4];
    for (int idx = threadIdx.x; idx < K * M4; idx += BS) {
        int k = idx / M4, m = idx - k * M4;
        Wl[idx] = (m < M) ? Wg[(size_t)k * M + m] : 0.f;
    }
    __syncthreads();

    int nrb = (N + 1) >> 1;                     // row-pairs
    int idx = blockIdx.x * BS + threadIdx.x;
    if (idx >= nrb * CG) return;
    int rb = idx / CG;                          // const divisor -> magic mul
    int cg = idx - rb * CG;
    int c0 = cg * 4;
    int r0 = rb * 2;
    bool two = (r0 + 1 < N);
    int r1 = two ? r0 + 1 : r0;
    const TIN* h0 = H + (size_t)r0 * LDIN;
    const TIN* h1 = H + (size_t)r1 * LDIN;

    float4 a0 = make_float4(0.f, 0.f, 0.f, 0.f);
    float4 a1 = make_float4(0.f, 0.f, 0.f, 0.f);

    constexpr int K4 = K & ~3;
    #pragma unroll 2
    for (int k = 0; k < K4; k += 4) {
        float4 p = load4(h0 + k);
        float4 q = load4(h1 + k);
        const float* wl = &Wl[k * M4 + c0];
        float4 w0 = *(const float4*)(wl);
        float4 w1 = *(const float4*)(wl + M4);
        float4 w2 = *(const float4*)(wl + 2 * M4);
        float4 w3 = *(const float4*)(wl + 3 * M4);
        fma4(a0, p.x, w0); fma4(a1, q.x, w0);
        fma4(a0, p.y, w1); fma4(a1, q.y, w1);
        fma4(a0, p.z, w2); fma4(a1, q.z, w2);
        fma4(a0, p.w, w3); fma4(a1, q.w, w3);
    }
    #pragma unroll
    for (int k = K4; k < K; ++k) {
        float p = (float)h0[k];
        float q = (float)h1[k];
        float4 w = *(const float4*)&Wl[k * M4 + c0];
        fma4(a0, p, w); fma4(a1, q, w);
    }

    // epilogue: bias/relu; zero-fill cols in [M, M4) (consumers read them).
    float* p0 = &a0.x;
    float* p1 = &a1.x;
    #pragma unroll
    for (int j = 0; j < 4; ++j) {
        int c = c0 + j;
        bool in = (c < M);
        float bb = (BIAS && in) ? bias[c] : 0.f;
        float v0 = in ? p0[j] + bb : 0.f;
        float v1 = in ? p1[j] + bb : 0.f;
        if (RELU) { v0 = fmaxf(v0, 0.f); v1 = fmaxf(v1, 0.f); }
        p0[j] = v0; p1[j] = v1;
    }
    store4(out + (size_t)r0 * LDOUT + c0, a0);
    if (two) store4(out + (size_t)r1 * LDOUT + c0, a1);
}

// ---------------- normalized aggregation ----------------
// out[i,:] = dinv_i^2*T[i,:] + sum_e w_e * T[src_e,:]  (+bias)(+relu)
template<typename TIN, typename TOUT, int M, int M4, int LDI, int LDO, bool BIAS, bool RELU>
__global__ __launch_bounds__(BS) void k_agg(const TIN* __restrict__ T, TOUT* __restrict__ out,
                                            const int* __restrict__ row_ptr, const uint2* __restrict__ entries,
                                            const float* __restrict__ dinv, const float* __restrict__ bias,
                                            int N) {
    constexpr int CG = M4 / 4;
    int idx = blockIdx.x * BS + threadIdx.x;
    if (idx >= N * CG) return;
    int i  = idx / CG;                // const divisor -> magic mul
    int cg = idx - i * CG;
    int c0 = cg * 4;

    float di = dinv[i];
    float4 t0 = load4(T + (size_t)i * LDI + c0);
    float w0 = di * di;
    float4 acc0 = make_float4(w0 * t0.x, w0 * t0.y, w0 * t0.z, w0 * t0.w);
    float4 acc1 = make_float4(0.f, 0.f, 0.f, 0.f);

    int e0 = row_ptr[i], e1 = row_ptr[i + 1];
    int e = e0;
    for (; e + 3 < e1; e += 4) {
        uint2 ea = entries[e];
        uint2 eb = entries[e + 1];
        uint2 ec = entries[e + 2];
        uint2 ed = entries[e + 3];
        float4 ta = load4(T + (size_t)ea.x * LDI + c0);
        float4 tb = load4(T + (size_t)eb.x * LDI + c0);
        float4 tc = load4(T + (size_t)ec.x * LDI + c0);
        float4 td = load4(T + (size_t)ed.x * LDI + c0);
        float wa = __uint_as_float(ea.y), wb = __uint_as_float(eb.y);
        float wc = __uint_as_float(ec.y), wd = __uint_as_float(ed.y);
        acc0.x = fmaf(wa, ta.x, acc0.x); acc0.y = fmaf(wa, ta.y, acc0.y);
        acc0.z = fmaf(wa, ta.z, acc0.z); acc0.w = fmaf(wa, ta.w, acc0.w);
        acc1.x = fmaf(wb, tb.x, acc1.x); acc1.y = fmaf(wb, tb.y, acc1.y);
        acc1.z = fmaf(wb, tb.z, acc1.z); acc1.w = fmaf(wb, tb.w, acc1.w);
        acc0.x = fmaf(wc, tc.x, acc0.x); acc0.y = fmaf(wc, tc.y, acc0.y);
        acc0.z = fmaf(wc, tc.z, acc0.z); acc0.w = fmaf(wc, tc.w, acc0.w);
        acc1.x = fmaf(wd, td.x, acc1.x); acc1.y = fmaf(wd, td.y, acc1.y);
        acc1.z = fmaf(wd, td.z, acc1.z); acc1.w = fmaf(wd, td.w, acc1.w);
    }
    for (; e < e1; ++e) {
        uint2 ea = entries[e];
        float4 ta = load4(T + (size_t)ea.x * LDI + c0);
        float wa = __uint_as_float(ea.y);
        acc0.x = fmaf(wa, ta.x, acc0.x); acc0.y = fmaf(wa, ta.y, acc0.y);
        acc0.z = fmaf(wa, ta.z, acc0.z); acc0.w = fmaf(wa, ta.w, acc0.w);
    }
    acc0.x += acc1.x; acc0.y += acc1.y; acc0.z += acc1.z; acc0.w += acc1.w;

    float* vp = &acc0.x;
    #pragma unroll
    for (int j = 0; j < 4; ++j) {
        if (BIAS && (c0 + j) < M) vp[j] += bias[c0 + j];
        if (RELU) vp[j] = fmaxf(vp[j], 0.f);
    }
    store4(out + (size_t)i * LDO + c0, acc0);
}

// ---------------- driver ----------------

extern "C" void kernel_launch(void* const* d_in, const int* in_sizes, int n_in,
                              void* d_out, int out_size, void* d_ws, size_t ws_size,
                              hipStream_t stream) {
    const float* x  = (const float*)d_in[0];
    const float* W1 = (const float*)d_in[1];
    const float* b1 = (const float*)d_in[2];
    const float* W2 = (const float*)d_in[3];
    const float* b2 = (const float*)d_in[4];
    const float* W3 = (const float*)d_in[5];
    const float* b3 = (const float*)d_in[6];
    const float* W4 = (const float*)d_in[7];
    const float* b4 = (const float*)d_in[8];
    const int* edge_index = (const int*)d_in[9];

    const int N = in_sizes[0] / 88;
    const int E = in_sizes[9] / 2;
    const int* src = edge_index;
    const int* dst = edge_index + E;

    const int nch = (E + CHUNK - 1) / CHUNK;            // 391
    const int bsz = (N + NB - 1) / NB;                  // 391 (< 512, 9-bit doff)
    const unsigned long long invB = ((1ull << 40) + bsz - 1) / bsz;

    char* p = (char*)d_ws;
    auto carve = [&](size_t bytes) { void* r = p; p += (bytes + 255) & ~(size_t)255; return r; };
    int*   cnt     = (int*)  carve((size_t)N * 4);
    float* dinv    = (float*)carve((size_t)N * 4);
    int*   row_ptr = (int*)  carve((size_t)(N + 1) * 4);
    int*   bsum    = (int*)  carve(4096);
    int*   bcounts = (int*)  carve((size_t)nch * NB * 4);
    unsigned* bbuf = (unsigned*)carve((size_t)nch * NB * CAP * 4);
    uint2* entries = (uint2*)carve((size_t)E * 8);
    _Float16* hA   = (_Float16*)carve((size_t)N * 68 * 2);
    _Float16* hB   = (_Float16*)carve((size_t)N * 68 * 2);
    _Float16* hC   = (_Float16*)carve((size_t)N * 68 * 2);

    int gN = (N + BS - 1) / BS;

    k_zero1 <<<gN, BS, 0, stream>>>(cnt, N);
    k_bucket<<<nch, BS, 0, stream>>>(src, dst, bbuf, bcounts, E, invB, bsz);
    k_cnt   <<<NB, FB, 0, stream>>>(bbuf, bcounts, cnt, nch, bsz, N);
    k_dinv  <<<gN, BS, 0, stream>>>(cnt, dinv, N);
    k_scan1 <<<gN, BS, 0, stream>>>(cnt, bsum, N);
    k_scan2 <<<1, 512, 0, stream>>>(bsum, gN);
    k_scan3 <<<gN, BS, 0, stream>>>(cnt, bsum, row_ptr, N);
    k_fill2 <<<NB, FB, 0, stream>>>(bbuf, bcounts, row_ptr, dinv, entries, nch, bsz, N);

    auto agg_grid  = [&](int CG) { return (N * CG + BS - 1) / BS; };
    auto gemm_grid = [&](int M)  { int M4 = (M + 3) & ~3; int CG = M4 / 4;
                                   return (((N + 1) / 2) * CG + BS - 1) / BS; };

    // G1: x(f32,88) @ W1 -> hA(f16, ld68)
    k_gemm<float, 88, 65, 88, 68, false, false, _Float16><<<gemm_grid(65), BS, 0, stream>>>(x, W1, nullptr, hA, N);
    // A1: agg(hA) +b1 +relu -> hB(f16, ld68)
    k_agg<_Float16, _Float16, 65, 68, 68, 68, true, true><<<agg_grid(17), BS, 0, stream>>>(hA, hB, row_ptr, entries, dinv, b1, N);
    // G2: hB @ W2 -> hC(f16, ld64: 128B rows -> exact 2-line gathers)
    k_gemm<_Float16, 65, 50, 68, 64, false, false, _Float16><<<gemm_grid(50), BS, 0, stream>>>(hB, W2, nullptr, hC, N);
    // A2: agg(hC) +b2 -> hA(f16, ld64)
    k_agg<_Float16, _Float16, 50, 52, 64, 64, true, false><<<agg_grid(13), BS, 0, stream>>>(hC, hA, row_ptr, entries, dinv, b2, N);
    // A3: agg(hA) -> hB(f16, ld52)
    k_agg<_Float16, _Float16, 50, 52, 64, 52, false, false><<<agg_grid(13), BS, 0, stream>>>(hA, hB, row_ptr, entries, dinv, nullptr, N);
    // G3: hB @ W3 +b3 +relu -> hC(f16, ld68)
    k_gemm<_Float16, 50, 65, 52, 68, true, true, _Float16><<<gemm_grid(65), BS, 0, stream>>>(hB, W3, b3, hC, N);
    // A4: agg(hC) -> hA(f16, ld68)
    k_agg<_Float16, _Float16, 65, 68, 68, 68, false, false><<<agg_grid(17), BS, 0, stream>>>(hC, hA, row_ptr, entries, dinv, nullptr, N);
    // G4: hA @ W4 +b4 -> d_out(f32, ld88)
    k_gemm<_Float16, 65, 88, 68, 88, true, false, float><<<gemm_grid(88), BS, 0, stream>>>(hA, W4, b4, (float*)d_out, N);
}

// Round 4
// 459.436 us; speedup vs baseline: 1.7636x; 1.0038x over previous
//
#include <hip/hip_runtime.h>

#define BS 256
#define FB 1024         // threads for bucket-parallel phases
#define NB 256          // dst-range buckets (one block each in phases 2/3)
#define CHUNK 4096      // edges per phase-1 block
#define CAP 64          // slots per (chunk,bucket); Poisson(16), +12 sigma
#define LCAP 8192       // entries per bucket in LDS; Poisson(6250), +24 sigma

using half8 = __attribute__((ext_vector_type(8))) _Float16;

// 16B row I/O: all intermediate layouts are padded so rows are 16B-aligned
// (ld72 for 65-col tensors, ld56 for 50-col). 8 cols per lane everywhere.
template<typename T>
__device__ __forceinline__ void load8f(const T* p, float (&d)[8]) {
    if constexpr (sizeof(T) == 4) {
        float4 a = *(const float4*)p;
        float4 b = *(const float4*)(p + 4);
        d[0] = a.x; d[1] = a.y; d[2] = a.z; d[3] = a.w;
        d[4] = b.x; d[5] = b.y; d[6] = b.z; d[7] = b.w;
    } else {
        half8 v = *(const half8*)p;
        #pragma unroll
        for (int j = 0; j < 8; ++j) d[j] = (float)v[j];
    }
}
template<typename T>
__device__ __forceinline__ void store8f(T* p, const float (&d)[8]) {
    if constexpr (sizeof(T) == 4) {
        *(float4*)p       = make_float4(d[0], d[1], d[2], d[3]);
        *(float4*)(p + 4) = make_float4(d[4], d[5], d[6], d[7]);
    } else {
        half8 h;
        #pragma unroll
        for (int j = 0; j < 8; ++j) h[j] = (_Float16)d[j];
        *(half8*)p = h;
    }
}

// ---------------- CSR build ----------------

__global__ __launch_bounds__(BS) void k_zero1(int* a, int n) {
    int i = blockIdx.x * BS + threadIdx.x;
    if (i < n) a[i] = 0;
}

// Phase 1: bucket edges into block-private regions (packed doff<<17|src).
__global__ __launch_bounds__(BS) void k_bucket(const int* __restrict__ src, const int* __restrict__ dst,
                                               unsigned* __restrict__ bbuf, int* __restrict__ bcounts,
                                               int E, unsigned long long invB, int bsz) {
    __shared__ int lcnt[NB];
    for (int t = threadIdx.x; t < NB; t += BS) lcnt[t] = 0;
    __syncthreads();
    int base_e = blockIdx.x * CHUNK;
    unsigned* mybuf = bbuf + (size_t)blockIdx.x * NB * CAP;
    #pragma unroll
    for (int j = 0; j < CHUNK / BS; ++j) {
        int e = base_e + j * BS + threadIdx.x;
        if (e < E) {
            int d = dst[e];
            int s = src[e];
            int b = (int)(((unsigned long long)(unsigned)d * invB) >> 40);
            int doff = d - b * bsz;                       // < 512 (9 bits)
            int pos = atomicAdd(&lcnt[b], 1);
            if (pos < CAP)                                // overflow ~impossible (+12 sigma)
                mybuf[b * CAP + pos] = ((unsigned)doff << 17) | (unsigned)s;
        }
    }
    __syncthreads();
    for (int t = threadIdx.x; t < NB; t += BS)
        bcounts[blockIdx.x * NB + t] = min(lcnt[t], CAP);
}

// Phase 2: per-bucket degree counts.
__global__ __launch_bounds__(FB) void k_cnt(const unsigned* __restrict__ bbuf, const int* __restrict__ bcounts,
                                            int* __restrict__ cnt, int nch, int bsz, int N) {
    __shared__ int lhist[512];
    for (int t = threadIdx.x; t < 512; t += FB) lhist[t] = 0;
    __syncthreads();
    int b = blockIdx.x;
    int lo = b * bsz;
    int total = nch * CAP;
    for (int idx = threadIdx.x; idx < total; idx += FB) {
        int seg = idx >> 6, slot = idx & 63;              // CAP == 64
        int c = bcounts[seg * NB + b];                    // wave-uniform
        if (slot < c)
            atomicAdd(&lhist[bbuf[((size_t)seg * NB + b) * CAP + slot] >> 17], 1);
    }
    __syncthreads();
    int hi = min(N, lo + bsz);
    for (int t = threadIdx.x; t < hi - lo; t += FB) cnt[lo + t] = lhist[t];
}

__global__ __launch_bounds__(BS) void k_dinv(const int* __restrict__ cnt, float* __restrict__ dinv, int N) {
    int i = blockIdx.x * BS + threadIdx.x;
    if (i < N) dinv[i] = rsqrtf((float)(cnt[i] + 1));   // +1 = self-loop
}

__global__ __launch_bounds__(BS) void k_scan1(const int* __restrict__ cnt, int* __restrict__ bsum, int N) {
    __shared__ int s[BS];
    int i = blockIdx.x * BS + threadIdx.x;
    s[threadIdx.x] = (i < N) ? cnt[i] : 0;
    __syncthreads();
    for (int off = BS / 2; off > 0; off >>= 1) {
        if (threadIdx.x < off) s[threadIdx.x] += s[threadIdx.x + off];
        __syncthreads();
    }
    if (threadIdx.x == 0) bsum[blockIdx.x] = s[0];
}

__global__ __launch_bounds__(512) void k_scan2(int* bsum, int nb) {
    __shared__ int s[512];
    int t = threadIdx.x;
    int v = (t < nb) ? bsum[t] : 0;
    s[t] = v;
    __syncthreads();
    for (int off = 1; off < 512; off <<= 1) {
        int u = (t >= off) ? s[t - off] : 0;
        __syncthreads();
        s[t] += u;
        __syncthreads();
    }
    if (t < nb) bsum[t] = s[t] - v;   // exclusive of self
}

__global__ __launch_bounds__(BS) void k_scan3(const int* __restrict__ cnt, const int* __restrict__ boff,
                                              int* __restrict__ row_ptr, int N) {
    __shared__ int s[BS];
    int t = threadIdx.x;
    int i = blockIdx.x * BS + t;
    int v = (i < N) ? cnt[i] : 0;
    s[t] = v;
    __syncthreads();
    for (int off = 1; off < BS; off <<= 1) {
        int u = (t >= off) ? s[t - off] : 0;
        __syncthreads();
        s[t] += u;
        __syncthreads();
    }
    int base = boff[blockIdx.x];
    if (i < N) row_ptr[i] = base + s[t] - v;
    if (i == N - 1) row_ptr[N] = base + s[t];
}

// Phase 3: counting-sort into LDS, stream out coalesced.
__global__ __launch_bounds__(FB) void k_fill2(const unsigned* __restrict__ bbuf, const int* __restrict__ bcounts,
                                              const int* __restrict__ row_ptr, const float* __restrict__ dinv,
                                              uint2* __restrict__ entries,
                                              int nch, int bsz, int N) {
    __shared__ int cur[512];
    __shared__ float ldinv[512];
    __shared__ unsigned sorted[LCAP];

    int b = blockIdx.x;
    int lo = b * bsz;
    int hi = min(N, lo + bsz);
    int gbase = row_ptr[lo];
    int tot = row_ptr[hi] - gbase;
    for (int t = threadIdx.x; t < hi - lo; t += FB) {
        cur[t] = row_ptr[lo + t] - gbase;
        ldinv[t] = dinv[lo + t];
    }
    __syncthreads();

    int total = nch * CAP;
    for (int idx = threadIdx.x; idx < total; idx += FB) {
        int seg = idx >> 6, slot = idx & 63;              // CAP == 64
        int c = bcounts[seg * NB + b];                    // wave-uniform
        if (slot < c) {
            unsigned u = bbuf[((size_t)seg * NB + b) * CAP + slot];
            int p = atomicAdd(&cur[u >> 17], 1);
            if (p < LCAP) sorted[p] = u;
        }
    }
    __syncthreads();

    for (int t = threadIdx.x; t < tot; t += FB) {
        unsigned u = sorted[t];
        int s = (int)(u & 0x1FFFFu);
        int doff = (int)(u >> 17);
        float w = dinv[s] * ldinv[doff];
        entries[gbase + t] = make_uint2((unsigned)s, __float_as_uint(w));
    }
}

// ---------------- dense transform ----------------
// out[N, LDOUT=M8] = H[N, LDIN] @ W[K, M] (+bias)(+relu).
// Thread = (row-pair, 8-col group). K-step 8, outer unroll 1 (full unroll of
// the k loop spilled: 356 MB scratch writes in round 1 -- keep it bounded).
// LDS W stride = M8+4 floats to break the 128B bank alias (was 3.57M
// SQ_LDS_BANK_CONFLICT with dense stride).
// All LDOUT pad cols [M, M8) are written as 0, so downstream 8-wide readers
// see valid zeros.
template<typename TIN, int K, int M, int LDIN, int LDOUT, bool BIAS, bool RELU, typename TOUT>
__global__ __launch_bounds__(BS) void k_gemm(const TIN* __restrict__ H, const float* __restrict__ Wg,
                                             const float* __restrict__ bias, TOUT* __restrict__ out, int N) {
    constexpr int M8 = (M + 7) & ~7;
    constexpr int MS = M8 + 4;                  // LDS stride (floats): bank stagger
    constexpr int CG = M8 / 8;
    __shared__ float Wl[K * MS];
    for (int idx = threadIdx.x; idx < K * MS; idx += BS) {
        int k = idx / MS, m = idx - k * MS;
        Wl[idx] = (m < M) ? Wg[(size_t)k * M + m] : 0.f;
    }
    __syncthreads();

    int nrb = (N + 1) >> 1;                     // row-pairs
    int idx = blockIdx.x * BS + threadIdx.x;
    if (idx >= nrb * CG) return;
    int rb = idx / CG;                          // const divisor -> magic mul
    int cg = idx - rb * CG;
    int c0 = cg * 8;
    int r0 = rb * 2;
    bool two = (r0 + 1 < N);
    int r1 = two ? r0 + 1 : r0;
    const TIN* h0 = H + (size_t)r0 * LDIN;
    const TIN* h1 = H + (size_t)r1 * LDIN;

    float acc0[8], acc1[8];
    #pragma unroll
    for (int m = 0; m < 8; ++m) { acc0[m] = 0.f; acc1[m] = 0.f; }

    constexpr int K8 = K & ~7;
    #pragma unroll 1
    for (int k = 0; k < K8; k += 8) {
        float p0[8], p1[8];
        load8f(h0 + k, p0);
        load8f(h1 + k, p1);
        #pragma unroll
        for (int j = 0; j < 8; ++j) {
            const float* wl = &Wl[(k + j) * MS + c0];
            float4 wa = *(const float4*)wl;
            float4 wb = *(const float4*)(wl + 4);
            const float wv[8] = {wa.x, wa.y, wa.z, wa.w, wb.x, wb.y, wb.z, wb.w};
            #pragma unroll
            for (int m = 0; m < 8; ++m) {
                acc0[m] = fmaf(p0[j], wv[m], acc0[m]);
                acc1[m] = fmaf(p1[j], wv[m], acc1[m]);
            }
        }
    }
    #pragma unroll
    for (int k = K8; k < K; ++k) {
        float pa = (float)h0[k];
        float pb = (float)h1[k];
        const float* wl = &Wl[k * MS + c0];
        float4 wa = *(const float4*)wl;
        float4 wb = *(const float4*)(wl + 4);
        const float wv[8] = {wa.x, wa.y, wa.z, wa.w, wb.x, wb.y, wb.z, wb.w};
        #pragma unroll
        for (int m = 0; m < 8; ++m) {
            acc0[m] = fmaf(pa, wv[m], acc0[m]);
            acc1[m] = fmaf(pb, wv[m], acc1[m]);
        }
    }

    // epilogue: bias/relu for real cols; zero for pad cols [M, M8).
    #pragma unroll
    for (int m = 0; m < 8; ++m) {
        int c = c0 + m;
        bool in = (c < M);
        float v0 = in ? acc0[m] : 0.f;
        float v1 = in ? acc1[m] : 0.f;
        if (BIAS && in) { float bb = bias[c]; v0 += bb; v1 += bb; }
        if (RELU) { v0 = fmaxf(v0, 0.f); v1 = fmaxf(v1, 0.f); }
        acc0[m] = v0; acc1[m] = v1;
    }
    store8f(out + (size_t)r0 * LDOUT + c0, acc0);
    if (two) store8f(out + (size_t)r1 * LDOUT + c0, acc1);
}

// ---------------- normalized aggregation ----------------
// out[i,:] = dinv_i^2*T[i,:] + sum_e w_e * T[src_e,:]  (+bias)(+relu)
// Latency-bound random gather (T doesn't fit per-XCD L2; served by L3 at
// ~600cy). Structure: 16B/lane (CG=M8/8), 8 edges in flight per chunk with
// clamped-index zero-weight tail padding (OOB lanes re-read entries[e1-1],
// L1-cached, weight 0 -> no divergent remainder, full ILP in tail).
template<typename TIN, typename TOUT, int M, int M8, int LDI, int LDO, bool BIAS, bool RELU>
__global__ __launch_bounds__(BS) void k_agg(const TIN* __restrict__ T, TOUT* __restrict__ out,
                                            const int* __restrict__ row_ptr, const uint2* __restrict__ entries,
                                            const float* __restrict__ dinv, const float* __restrict__ bias,
                                            int N) {
    constexpr int CG = M8 / 8;
    int idx = blockIdx.x * BS + threadIdx.x;
    if (idx >= N * CG) return;
    int i  = idx / CG;                // const divisor -> magic mul
    int cg = idx - i * CG;
    int c0 = cg * 8;

    float di = dinv[i];
    float w0 = di * di;
    float t0[8];
    load8f(T + (size_t)i * LDI + c0, t0);
    float a0[8], a1[8];
    #pragma unroll
    for (int m = 0; m < 8; ++m) { a0[m] = w0 * t0[m]; a1[m] = 0.f; }

    int e0 = row_ptr[i], e1 = row_ptr[i + 1];
    for (int e = e0; e < e1; e += 8) {
        unsigned sidx[8];
        float w[8];
        #pragma unroll
        for (int j = 0; j < 8; ++j) {
            int ee = e + j;
            int ec = (ee < e1) ? ee : (e1 - 1);
            uint2 u = entries[ec];
            sidx[j] = u.x;
            w[j] = (ee < e1) ? __uint_as_float(u.y) : 0.f;
        }
        #pragma unroll
        for (int j = 0; j < 8; ++j) {
            float g[8];
            load8f(T + (size_t)sidx[j] * LDI + c0, g);
            if (j & 1) {
                #pragma unroll
                for (int m = 0; m < 8; ++m) a1[m] = fmaf(w[j], g[m], a1[m]);
            } else {
                #pragma unroll
                for (int m = 0; m < 8; ++m) a0[m] = fmaf(w[j], g[m], a0[m]);
            }
        }
    }

    #pragma unroll
    for (int m = 0; m < 8; ++m) {
        float v = a0[m] + a1[m];
        if (BIAS && (c0 + m) < M) v += bias[c0 + m];
        if (RELU) v = fmaxf(v, 0.f);
        a0[m] = v;
    }
    store8f(out + (size_t)i * LDO + c0, a0);
}

// ---------------- driver ----------------

extern "C" void kernel_launch(void* const* d_in, const int* in_sizes, int n_in,
                              void* d_out, int out_size, void* d_ws, size_t ws_size,
                              hipStream_t stream) {
    const float* x  = (const float*)d_in[0];
    const float* W1 = (const float*)d_in[1];
    const float* b1 = (const float*)d_in[2];
    const float* W2 = (const float*)d_in[3];
    const float* b2 = (const float*)d_in[4];
    const float* W3 = (const float*)d_in[5];
    const float* b3 = (const float*)d_in[6];
    const float* W4 = (const float*)d_in[7];
    const float* b4 = (const float*)d_in[8];
    const int* edge_index = (const int*)d_in[9];

    const int N = in_sizes[0] / 88;
    const int E = in_sizes[9] / 2;
    const int* src = edge_index;
    const int* dst = edge_index + E;

    const int nch = (E + CHUNK - 1) / CHUNK;            // 391
    const int bsz = (N + NB - 1) / NB;                  // 391 (< 512, 9-bit doff)
    const unsigned long long invB = ((1ull << 40) + bsz - 1) / bsz;

    // Workspace layout. The CSR scratch (bcounts+bbuf, ~26 MB) is dead after
    // k_fill2; hA/hB/hC are first written by G1, which launches after k_fill2
    // on the same stream -> the h-buffers legally ALIAS the CSR scratch.
    // This keeps total footprint (~58 MB) well below the previously-passing
    // round-2 layout (~82 MB); round 3's +2.4 MB growth past that layout is
    // the prime suspect for the container-killing fault.
    auto al = [](size_t b) { return (b + 255) & ~(size_t)255; };
    char* p = (char*)d_ws;
    auto carve = [&](size_t bytes) { void* r = p; p += (bytes + 255) & ~(size_t)255; return r; };
    int*   cnt     = (int*)  carve((size_t)N * 4);
    float* dinv    = (float*)carve((size_t)N * 4);
    int*   row_ptr = (int*)  carve((size_t)(N + 1) * 4);
    int*   bsum    = (int*)  carve(4096);
    uint2* entries = (uint2*)carve((size_t)E * 8);

    char* ub = p;                                        // union region base
    int*      bcounts = (int*)ub;
    unsigned* bbuf    = (unsigned*)(ub + al((size_t)nch * NB * 4));
    size_t csr_bytes  = al((size_t)nch * NB * 4) + al((size_t)nch * NB * CAP * 4);

    size_t hbytes = al((size_t)N * 72 * 2);
    _Float16* hA = (_Float16*)ub;                        // aliases bcounts/bbuf
    _Float16* hB = (_Float16*)(ub + hbytes);
    _Float16* hC = (_Float16*)(ub + 2 * hbytes);
    size_t h_bytes_tot = 3 * hbytes;

    p = ub + (csr_bytes > h_bytes_tot ? csr_bytes : h_bytes_tot);
    (void)p; (void)ws_size;

    int gN = (N + BS - 1) / BS;

    k_zero1 <<<gN, BS, 0, stream>>>(cnt, N);
    k_bucket<<<nch, BS, 0, stream>>>(src, dst, bbuf, bcounts, E, invB, bsz);
    k_cnt   <<<NB, FB, 0, stream>>>(bbuf, bcounts, cnt, nch, bsz, N);
    k_dinv  <<<gN, BS, 0, stream>>>(cnt, dinv, N);
    k_scan1 <<<gN, BS, 0, stream>>>(cnt, bsum, N);
    k_scan2 <<<1, 512, 0, stream>>>(bsum, gN);
    k_scan3 <<<gN, BS, 0, stream>>>(cnt, bsum, row_ptr, N);
    k_fill2 <<<NB, FB, 0, stream>>>(bbuf, bcounts, row_ptr, dinv, entries, nch, bsz, N);
    // --- bcounts/bbuf dead from here; hA/hB/hC reuse their storage ---

    auto agg_grid  = [&](int CG) { return (N * CG + BS - 1) / BS; };
    auto gemm_grid = [&](int M)  { int M8 = (M + 7) & ~7; int CG = M8 / 8;
                                   return (((N + 1) / 2) * CG + BS - 1) / BS; };

    // G1: x(f32, ld88) @ W1 -> hA(f16, ld72)
    k_gemm<float, 88, 65, 88, 72, false, false, _Float16><<<gemm_grid(65), BS, 0, stream>>>(x, W1, nullptr, hA, N);
    // A1: agg(hA) +b1 +relu -> hB(f16, ld72)
    k_agg<_Float16, _Float16, 65, 72, 72, 72, true, true><<<agg_grid(9), BS, 0, stream>>>(hA, hB, row_ptr, entries, dinv, b1, N);
    // G2: hB @ W2 -> hC(f16, ld56)
    k_gemm<_Float16, 65, 50, 72, 56, false, false, _Float16><<<gemm_grid(50), BS, 0, stream>>>(hB, W2, nullptr, hC, N);
    // A2: agg(hC) +b2 -> hA(f16, ld56)
    k_agg<_Float16, _Float16, 50, 56, 56, 56, true, false><<<agg_grid(7), BS, 0, stream>>>(hC, hA, row_ptr, entries, dinv, b2, N);
    // A3: agg(hA) -> hB(f16, ld56)
    k_agg<_Float16, _Float16, 50, 56, 56, 56, false, false><<<agg_grid(7), BS, 0, stream>>>(hA, hB, row_ptr, entries, dinv, nullptr, N);
    // G3: hB @ W3 +b3 +relu -> hC(f16, ld72)
    k_gemm<_Float16, 50, 65, 56, 72, true, true, _Float16><<<gemm_grid(65), BS, 0, stream>>>(hB, W3, b3, hC, N);
    // A4: agg(hC) -> hA(f16, ld72)
    k_agg<_Float16, _Float16, 65, 72, 72, 72, false, false><<<agg_grid(9), BS, 0, stream>>>(hC, hA, row_ptr, entries, dinv, nullptr, N);
    // G4: hA @ W4 +b4 -> d_out(f32, ld88)
    k_gemm<_Float16, 65, 88, 72, 88, true, false, float><<<gemm_grid(88), BS, 0, stream>>>(hA, W4, b4, (float*)d_out, N);
}

// Round 5
// 455.973 us; speedup vs baseline: 1.7770x; 1.0076x over previous
//
#include <hip/hip_runtime.h>

#define BS 256
#define FB 1024         // threads for bucket-parallel phases
#define NB 256          // dst-range buckets (one block each in phases 2/3)
#define CHUNK 4096      // edges per phase-1 block
#define CAP 64          // slots per (chunk,bucket); Poisson(16), +12 sigma
#define LCAP 8192       // entries per bucket in LDS; Poisson(6250), +24 sigma

using half8 = __attribute__((ext_vector_type(8))) _Float16;

// 16B row I/O: all intermediate layouts are padded so rows are 16B-aligned
// (ld72 for 65-col tensors, ld56 for 50-col). 8 cols per lane everywhere.
template<typename T>
__device__ __forceinline__ void load8f(const T* p, float (&d)[8]) {
    if constexpr (sizeof(T) == 4) {
        float4 a = *(const float4*)p;
        float4 b = *(const float4*)(p + 4);
        d[0] = a.x; d[1] = a.y; d[2] = a.z; d[3] = a.w;
        d[4] = b.x; d[5] = b.y; d[6] = b.z; d[7] = b.w;
    } else {
        half8 v = *(const half8*)p;
        #pragma unroll
        for (int j = 0; j < 8; ++j) d[j] = (float)v[j];
    }
}
template<typename T>
__device__ __forceinline__ void store8f(T* p, const float (&d)[8]) {
    if constexpr (sizeof(T) == 4) {
        *(float4*)p       = make_float4(d[0], d[1], d[2], d[3]);
        *(float4*)(p + 4) = make_float4(d[4], d[5], d[6], d[7]);
    } else {
        half8 h;
        #pragma unroll
        for (int j = 0; j < 8; ++j) h[j] = (_Float16)d[j];
        *(half8*)p = h;
    }
}

// ---------------- CSR build ----------------

// Phase 1: bucket edges into block-private regions (packed doff<<17|src).
__global__ __launch_bounds__(BS) void k_bucket(const int* __restrict__ src, const int* __restrict__ dst,
                                               unsigned* __restrict__ bbuf, int* __restrict__ bcounts,
                                               int E, unsigned long long invB, int bsz) {
    __shared__ int lcnt[NB];
    for (int t = threadIdx.x; t < NB; t += BS) lcnt[t] = 0;
    __syncthreads();
    int base_e = blockIdx.x * CHUNK;
    unsigned* mybuf = bbuf + (size_t)blockIdx.x * NB * CAP;
    #pragma unroll
    for (int j = 0; j < CHUNK / BS; ++j) {
        int e = base_e + j * BS + threadIdx.x;
        if (e < E) {
            int d = dst[e];
            int s = src[e];
            int b = (int)(((unsigned long long)(unsigned)d * invB) >> 40);
            int doff = d - b * bsz;                       // < 512 (9 bits)
            int pos = atomicAdd(&lcnt[b], 1);
            if (pos < CAP)                                // overflow ~impossible (+12 sigma)
                mybuf[b * CAP + pos] = ((unsigned)doff << 17) | (unsigned)s;
        }
    }
    __syncthreads();
    for (int t = threadIdx.x; t < NB; t += BS)
        bcounts[blockIdx.x * NB + t] = min(lcnt[t], CAP);
}

// Phase 2: per-bucket degree counts. Fully overwrites cnt[0..N) (every dst
// index belongs to exactly one bucket), so no separate zero kernel is needed.
__global__ __launch_bounds__(FB) void k_cnt(const unsigned* __restrict__ bbuf, const int* __restrict__ bcounts,
                                            int* __restrict__ cnt, int nch, int bsz, int N) {
    __shared__ int lhist[512];
    for (int t = threadIdx.x; t < 512; t += FB) lhist[t] = 0;
    __syncthreads();
    int b = blockIdx.x;
    int lo = b * bsz;
    int total = nch * CAP;
    for (int idx = threadIdx.x; idx < total; idx += FB) {
        int seg = idx >> 6, slot = idx & 63;              // CAP == 64
        int c = bcounts[seg * NB + b];                    // wave-uniform
        if (slot < c)
            atomicAdd(&lhist[bbuf[((size_t)seg * NB + b) * CAP + slot] >> 17], 1);
    }
    __syncthreads();
    int hi = min(N, lo + bsz);
    for (int t = threadIdx.x; t < hi - lo; t += FB) cnt[lo + t] = lhist[t];
}

// scan1 also emits dinv (folded former k_dinv: saves a launch + a cnt re-read).
__global__ __launch_bounds__(BS) void k_scan1(const int* __restrict__ cnt, int* __restrict__ bsum,
                                              float* __restrict__ dinv, int N) {
    __shared__ int s[BS];
    int i = blockIdx.x * BS + threadIdx.x;
    int v = (i < N) ? cnt[i] : 0;
    if (i < N) dinv[i] = rsqrtf((float)(v + 1));   // +1 = self-loop
    s[threadIdx.x] = v;
    __syncthreads();
    for (int off = BS / 2; off > 0; off >>= 1) {
        if (threadIdx.x < off) s[threadIdx.x] += s[threadIdx.x + off];
        __syncthreads();
    }
    if (threadIdx.x == 0) bsum[blockIdx.x] = s[0];
}

__global__ __launch_bounds__(512) void k_scan2(int* bsum, int nb) {
    __shared__ int s[512];
    int t = threadIdx.x;
    int v = (t < nb) ? bsum[t] : 0;
    s[t] = v;
    __syncthreads();
    for (int off = 1; off < 512; off <<= 1) {
        int u = (t >= off) ? s[t - off] : 0;
        __syncthreads();
        s[t] += u;
        __syncthreads();
    }
    if (t < nb) bsum[t] = s[t] - v;   // exclusive of self
}

__global__ __launch_bounds__(BS) void k_scan3(const int* __restrict__ cnt, const int* __restrict__ boff,
                                              int* __restrict__ row_ptr, int N) {
    __shared__ int s[BS];
    int t = threadIdx.x;
    int i = blockIdx.x * BS + t;
    int v = (i < N) ? cnt[i] : 0;
    s[t] = v;
    __syncthreads();
    for (int off = 1; off < BS; off <<= 1) {
        int u = (t >= off) ? s[t - off] : 0;
        __syncthreads();
        s[t] += u;
        __syncthreads();
    }
    int base = boff[blockIdx.x];
    if (i < N) row_ptr[i] = base + s[t] - v;
    if (i == N - 1) row_ptr[N] = base + s[t];
}

// Phase 3: counting-sort into LDS, stream out coalesced.
__global__ __launch_bounds__(FB) void k_fill2(const unsigned* __restrict__ bbuf, const int* __restrict__ bcounts,
                                              const int* __restrict__ row_ptr, const float* __restrict__ dinv,
                                              uint2* __restrict__ entries,
                                              int nch, int bsz, int N) {
    __shared__ int cur[512];
    __shared__ float ldinv[512];
    __shared__ unsigned sorted[LCAP];

    int b = blockIdx.x;
    int lo = b * bsz;
    int hi = min(N, lo + bsz);
    int gbase = row_ptr[lo];
    int tot = row_ptr[hi] - gbase;
    for (int t = threadIdx.x; t < hi - lo; t += FB) {
        cur[t] = row_ptr[lo + t] - gbase;
        ldinv[t] = dinv[lo + t];
    }
    __syncthreads();

    int total = nch * CAP;
    for (int idx = threadIdx.x; idx < total; idx += FB) {
        int seg = idx >> 6, slot = idx & 63;              // CAP == 64
        int c = bcounts[seg * NB + b];                    // wave-uniform
        if (slot < c) {
            unsigned u = bbuf[((size_t)seg * NB + b) * CAP + slot];
            int p = atomicAdd(&cur[u >> 17], 1);
            if (p < LCAP) sorted[p] = u;
        }
    }
    __syncthreads();

    for (int t = threadIdx.x; t < tot; t += FB) {
        unsigned u = sorted[t];
        int s = (int)(u & 0x1FFFFu);
        int doff = (int)(u >> 17);
        float w = dinv[s] * ldinv[doff];
        entries[gbase + t] = make_uint2((unsigned)s, __float_as_uint(w));
    }
}

// ---------------- dense transform ----------------
// out[N, LDOUT=M8] = H[N, LDIN] @ W[K, M] (+bias)(+relu).
// Thread = (row-QUAD, 8-col group): 32 independent FMA chains, 256 FMAs per
// K-step per thread -> ~64 issue-cycles of VALU per K-step per wave, enough
// to hide L1/LDS latency even at ~3 waves/SIMD (round-2 G1 showed the 2-row
// variant was latency-stalled: VALUBusy 31%, 56 us vs ~8 us floor).
// W in LDS is CG-MAJOR: Wl[cg][k][8] with a 4-float pad per cg block.
// Bank math: cg-block stride = K*8+4 floats -> stride%32 in {4,12,20} for all
// shapes here -> the <=11 distinct lane addresses per ds_read spread over
// banks with <=2-way aliasing (2-way is free), and a thread's k-walk is a
// sequential 32B stream. (Old row-major layout had 32B cg-stride -> 3-way
// alias on banks {0,8,16,24}: the measured 3.57M SQ_LDS_BANK_CONFLICT.)
// K-loop outer unroll kept at 1: full unroll spilled in round 1 (356 MB
// scratch WRITE_SIZE). Pad cols [M, M8) written as 0 for downstream readers.
template<typename TIN, int K, int M, int LDIN, int LDOUT, bool BIAS, bool RELU, typename TOUT>
__global__ __launch_bounds__(BS) void k_gemm(const TIN* __restrict__ H, const float* __restrict__ Wg,
                                             const float* __restrict__ bias, TOUT* __restrict__ out, int N) {
    constexpr int M8 = (M + 7) & ~7;
    constexpr int CG = M8 / 8;
    constexpr int WSTR = K * 8 + 4;             // floats per cg block (bank stagger)
    __shared__ float Wl[CG * WSTR];
    for (int idx = threadIdx.x; idx < CG * WSTR; idx += BS) {
        int cg = idx / WSTR, rem = idx - cg * WSTR;
        int k = rem >> 3, j = rem & 7;
        int m = cg * 8 + j;
        Wl[idx] = (rem < K * 8 && m < M) ? Wg[(size_t)k * M + m] : 0.f;
    }
    __syncthreads();

    int nrq = (N + 3) >> 2;                     // row-quads
    int idx = blockIdx.x * BS + threadIdx.x;
    if (idx >= nrq * CG) return;
    int rq = idx / CG;                          // const divisor -> magic mul
    int cg = idx - rq * CG;
    int c0 = cg * 8;
    int r0 = rq * 4;
    const float* wb = &Wl[cg * WSTR];

    const TIN* h[4];
    #pragma unroll
    for (int r = 0; r < 4; ++r) {
        int rr = r0 + r; rr = (rr < N) ? rr : (N - 1);   // clamp: safe loads
        h[r] = H + (size_t)rr * LDIN;
    }

    float acc[4][8];
    #pragma unroll
    for (int r = 0; r < 4; ++r)
        #pragma unroll
        for (int m = 0; m < 8; ++m) acc[r][m] = 0.f;

    constexpr int K8 = K & ~7;
    #pragma unroll 1
    for (int k = 0; k < K8; k += 8) {
        float p[4][8];
        load8f(h[0] + k, p[0]);
        load8f(h[1] + k, p[1]);
        load8f(h[2] + k, p[2]);
        load8f(h[3] + k, p[3]);
        const float* wl = wb + k * 8;
        #pragma unroll
        for (int j = 0; j < 8; ++j) {
            float4 wa = *(const float4*)(wl + j * 8);
            float4 wc = *(const float4*)(wl + j * 8 + 4);
            const float wv[8] = {wa.x, wa.y, wa.z, wa.w, wc.x, wc.y, wc.z, wc.w};
            #pragma unroll
            for (int r = 0; r < 4; ++r)
                #pragma unroll
                for (int m = 0; m < 8; ++m)
                    acc[r][m] = fmaf(p[r][j], wv[m], acc[r][m]);
        }
    }
    #pragma unroll
    for (int k = K8; k < K; ++k) {
        const float* wl = wb + k * 8;
        float4 wa = *(const float4*)(wl);
        float4 wc = *(const float4*)(wl + 4);
        const float wv[8] = {wa.x, wa.y, wa.z, wa.w, wc.x, wc.y, wc.z, wc.w};
        #pragma unroll
        for (int r = 0; r < 4; ++r) {
            float pv = (float)h[r][k];
            #pragma unroll
            for (int m = 0; m < 8; ++m)
                acc[r][m] = fmaf(pv, wv[m], acc[r][m]);
        }
    }

    // epilogue: bias/relu for real cols; zero for pad cols [M, M8).
    #pragma unroll
    for (int r = 0; r < 4; ++r) {
        int rr = r0 + r;
        if (rr >= N) break;
        float v[8];
        #pragma unroll
        for (int m = 0; m < 8; ++m) {
            int c = c0 + m;
            bool in = (c < M);
            float x = in ? acc[r][m] : 0.f;
            if (BIAS && in) x += bias[c];
            if (RELU) x = fmaxf(x, 0.f);
            v[m] = x;
        }
        store8f(out + (size_t)rr * LDOUT + c0, v);
    }
}

// ---------------- normalized aggregation ----------------
// out[i,:] = dinv_i^2*T[i,:] + sum_e w_e * T[src_e,:]  (+bias)(+relu)
// UNCHANGED control this round. Measured wall: duration == FETCH / ~2.9 TB/s
// in two structurally different variants (71% and 34% occupancy) -> bound by
// random 64B-line service rate (T=14.4MB >> 4MB per-XCD L2, 72% miss to L3).
template<typename TIN, typename TOUT, int M, int M8, int LDI, int LDO, bool BIAS, bool RELU>
__global__ __launch_bounds__(BS) void k_agg(const TIN* __restrict__ T, TOUT* __restrict__ out,
                                            const int* __restrict__ row_ptr, const uint2* __restrict__ entries,
                                            const float* __restrict__ dinv, const float* __restrict__ bias,
                                            int N) {
    constexpr int CG = M8 / 8;
    int idx = blockIdx.x * BS + threadIdx.x;
    if (idx >= N * CG) return;
    int i  = idx / CG;                // const divisor -> magic mul
    int cg = idx - i * CG;
    int c0 = cg * 8;

    float di = dinv[i];
    float w0 = di * di;
    float t0[8];
    load8f(T + (size_t)i * LDI + c0, t0);
    float a0[8], a1[8];
    #pragma unroll
    for (int m = 0; m < 8; ++m) { a0[m] = w0 * t0[m]; a1[m] = 0.f; }

    int e0 = row_ptr[i], e1 = row_ptr[i + 1];
    for (int e = e0; e < e1; e += 8) {
        unsigned sidx[8];
        float w[8];
        #pragma unroll
        for (int j = 0; j < 8; ++j) {
            int ee = e + j;
            int ec = (ee < e1) ? ee : (e1 - 1);
            uint2 u = entries[ec];
            sidx[j] = u.x;
            w[j] = (ee < e1) ? __uint_as_float(u.y) : 0.f;
        }
        #pragma unroll
        for (int j = 0; j < 8; ++j) {
            float g[8];
            load8f(T + (size_t)sidx[j] * LDI + c0, g);
            if (j & 1) {
                #pragma unroll
                for (int m = 0; m < 8; ++m) a1[m] = fmaf(w[j], g[m], a1[m]);
            } else {
                #pragma unroll
                for (int m = 0; m < 8; ++m) a0[m] = fmaf(w[j], g[m], a0[m]);
            }
        }
    }

    #pragma unroll
    for (int m = 0; m < 8; ++m) {
        float v = a0[m] + a1[m];
        if (BIAS && (c0 + m) < M) v += bias[c0 + m];
        if (RELU) v = fmaxf(v, 0.f);
        a0[m] = v;
    }
    store8f(out + (size_t)i * LDO + c0, a0);
}

// ---------------- driver ----------------

extern "C" void kernel_launch(void* const* d_in, const int* in_sizes, int n_in,
                              void* d_out, int out_size, void* d_ws, size_t ws_size,
                              hipStream_t stream) {
    const float* x  = (const float*)d_in[0];
    const float* W1 = (const float*)d_in[1];
    const float* b1 = (const float*)d_in[2];
    const float* W2 = (const float*)d_in[3];
    const float* b2 = (const float*)d_in[4];
    const float* W3 = (const float*)d_in[5];
    const float* b3 = (const float*)d_in[6];
    const float* W4 = (const float*)d_in[7];
    const float* b4 = (const float*)d_in[8];
    const int* edge_index = (const int*)d_in[9];

    const int N = in_sizes[0] / 88;
    const int E = in_sizes[9] / 2;
    const int* src = edge_index;
    const int* dst = edge_index + E;

    const int nch = (E + CHUNK - 1) / CHUNK;            // 391
    const int bsz = (N + NB - 1) / NB;                  // 391 (< 512, 9-bit doff)
    const unsigned long long invB = ((1ull << 40) + bsz - 1) / bsz;

    // Workspace layout (round-4 verified): CSR scratch (bcounts+bbuf) is dead
    // after k_fill2; hA/hB/hC are first written by G1 (later on the same
    // stream) -> h-buffers alias the CSR scratch. Total ~58 MB.
    auto al = [](size_t b) { return (b + 255) & ~(size_t)255; };
    char* p = (char*)d_ws;
    auto carve = [&](size_t bytes) { void* r = p; p += (bytes + 255) & ~(size_t)255; return r; };
    int*   cnt     = (int*)  carve((size_t)N * 4);
    float* dinv    = (float*)carve((size_t)N * 4);
    int*   row_ptr = (int*)  carve((size_t)(N + 1) * 4);
    int*   bsum    = (int*)  carve(4096);
    uint2* entries = (uint2*)carve((size_t)E * 8);

    char* ub = p;                                        // union region base
    int*      bcounts = (int*)ub;
    unsigned* bbuf    = (unsigned*)(ub + al((size_t)nch * NB * 4));
    size_t csr_bytes  = al((size_t)nch * NB * 4) + al((size_t)nch * NB * CAP * 4);

    size_t hbytes = al((size_t)N * 72 * 2);
    _Float16* hA = (_Float16*)ub;                        // aliases bcounts/bbuf
    _Float16* hB = (_Float16*)(ub + hbytes);
    _Float16* hC = (_Float16*)(ub + 2 * hbytes);
    size_t h_bytes_tot = 3 * hbytes;

    p = ub + (csr_bytes > h_bytes_tot ? csr_bytes : h_bytes_tot);
    (void)p; (void)ws_size;

    int gN = (N + BS - 1) / BS;

    k_bucket<<<nch, BS, 0, stream>>>(src, dst, bbuf, bcounts, E, invB, bsz);
    k_cnt   <<<NB, FB, 0, stream>>>(bbuf, bcounts, cnt, nch, bsz, N);
    k_scan1 <<<gN, BS, 0, stream>>>(cnt, bsum, dinv, N);
    k_scan2 <<<1, 512, 0, stream>>>(bsum, gN);
    k_scan3 <<<gN, BS, 0, stream>>>(cnt, bsum, row_ptr, N);
    k_fill2 <<<NB, FB, 0, stream>>>(bbuf, bcounts, row_ptr, dinv, entries, nch, bsz, N);
    // --- bcounts/bbuf dead from here; hA/hB/hC reuse their storage ---

    auto agg_grid  = [&](int CG) { return (N * CG + BS - 1) / BS; };
    auto gemm_grid = [&](int M)  { int M8 = (M + 7) & ~7; int CG = M8 / 8;
                                   return (((N + 3) / 4) * CG + BS - 1) / BS; };

    // G1: x(f32, ld88) @ W1 -> hA(f16, ld72)
    k_gemm<float, 88, 65, 88, 72, false, false, _Float16><<<gemm_grid(65), BS, 0, stream>>>(x, W1, nullptr, hA, N);
    // A1: agg(hA) +b1 +relu -> hB(f16, ld72)
    k_agg<_Float16, _Float16, 65, 72, 72, 72, true, true><<<agg_grid(9), BS, 0, stream>>>(hA, hB, row_ptr, entries, dinv, b1, N);
    // G2: hB @ W2 -> hC(f16, ld56)
    k_gemm<_Float16, 65, 50, 72, 56, false, false, _Float16><<<gemm_grid(50), BS, 0, stream>>>(hB, W2, nullptr, hC, N);
    // A2: agg(hC) +b2 -> hA(f16, ld56)
    k_agg<_Float16, _Float16, 50, 56, 56, 56, true, false><<<agg_grid(7), BS, 0, stream>>>(hC, hA, row_ptr, entries, dinv, b2, N);
    // A3: agg(hA) -> hB(f16, ld56)
    k_agg<_Float16, _Float16, 50, 56, 56, 56, false, false><<<agg_grid(7), BS, 0, stream>>>(hA, hB, row_ptr, entries, dinv, nullptr, N);
    // G3: hB @ W3 +b3 +relu -> hC(f16, ld72)
    k_gemm<_Float16, 50, 65, 56, 72, true, true, _Float16><<<gemm_grid(65), BS, 0, stream>>>(hB, W3, b3, hC, N);
    // A4: agg(hC) -> hA(f16, ld72)
    k_agg<_Float16, _Float16, 65, 72, 72, 72, false, false><<<agg_grid(9), BS, 0, stream>>>(hC, hA, row_ptr, entries, dinv, nullptr, N);
    // G4: hA @ W4 +b4 -> d_out(f32, ld88)
    k_gemm<_Float16, 65, 88, 72, 88, true, false, float><<<gemm_grid(88), BS, 0, stream>>>(hA, W4, b4, (float*)d_out, N);
}

// Round 6
// 449.374 us; speedup vs baseline: 1.8031x; 1.0147x over previous
//
#include <hip/hip_runtime.h>

#define BS 256
#define FB 1024         // threads for bucket-parallel phases
#define NB 256          // dst-range buckets (one block each in phases 2/3)
#define CHUNK 4096      // edges per phase-1 block
#define CAP 64          // slots per (chunk,bucket); Poisson(16), +12 sigma
#define LCAP 8192       // entries per bucket in LDS; Poisson(6250), +24 sigma

using half8 = __attribute__((ext_vector_type(8))) _Float16;

// 16B row I/O: intermediate layouts padded to 16B rows (ld72 for 65-col,
// ld56 for 50-col). 8 cols per lane everywhere.
template<typename T>
__device__ __forceinline__ void load8f(const T* p, float (&d)[8]) {
    if constexpr (sizeof(T) == 4) {
        float4 a = *(const float4*)p;
        float4 b = *(const float4*)(p + 4);
        d[0] = a.x; d[1] = a.y; d[2] = a.z; d[3] = a.w;
        d[4] = b.x; d[5] = b.y; d[6] = b.z; d[7] = b.w;
    } else {
        half8 v = *(const half8*)p;
        #pragma unroll
        for (int j = 0; j < 8; ++j) d[j] = (float)v[j];
    }
}
template<typename T>
__device__ __forceinline__ void store8f(T* p, const float (&d)[8]) {
    if constexpr (sizeof(T) == 4) {
        *(float4*)p       = make_float4(d[0], d[1], d[2], d[3]);
        *(float4*)(p + 4) = make_float4(d[4], d[5], d[6], d[7]);
    } else {
        half8 h;
        #pragma unroll
        for (int j = 0; j < 8; ++j) h[j] = (_Float16)d[j];
        *(half8*)p = h;
    }
}

// ---------------- CSR build ----------------

__global__ __launch_bounds__(BS) void k_bucket(const int* __restrict__ src, const int* __restrict__ dst,
                                               unsigned* __restrict__ bbuf, int* __restrict__ bcounts,
                                               int E, unsigned long long invB, int bsz) {
    __shared__ int lcnt[NB];
    for (int t = threadIdx.x; t < NB; t += BS) lcnt[t] = 0;
    __syncthreads();
    int base_e = blockIdx.x * CHUNK;
    unsigned* mybuf = bbuf + (size_t)blockIdx.x * NB * CAP;
    #pragma unroll
    for (int j = 0; j < CHUNK / BS; ++j) {
        int e = base_e + j * BS + threadIdx.x;
        if (e < E) {
            int d = dst[e];
            int s = src[e];
            int b = (int)(((unsigned long long)(unsigned)d * invB) >> 40);
            int doff = d - b * bsz;                       // < 512 (9 bits)
            int pos = atomicAdd(&lcnt[b], 1);
            if (pos < CAP)                                // overflow ~impossible (+12 sigma)
                mybuf[b * CAP + pos] = ((unsigned)doff << 17) | (unsigned)s;
        }
    }
    __syncthreads();
    for (int t = threadIdx.x; t < NB; t += BS)
        bcounts[blockIdx.x * NB + t] = min(lcnt[t], CAP);
}

// Phase 2: per-bucket degree counts. Fully overwrites cnt[0..N).
__global__ __launch_bounds__(FB) void k_cnt(const unsigned* __restrict__ bbuf, const int* __restrict__ bcounts,
                                            int* __restrict__ cnt, int nch, int bsz, int N) {
    __shared__ int lhist[512];
    for (int t = threadIdx.x; t < 512; t += FB) lhist[t] = 0;
    __syncthreads();
    int b = blockIdx.x;
    int lo = b * bsz;
    int total = nch * CAP;
    for (int idx = threadIdx.x; idx < total; idx += FB) {
        int seg = idx >> 6, slot = idx & 63;              // CAP == 64
        int c = bcounts[seg * NB + b];                    // wave-uniform
        if (slot < c)
            atomicAdd(&lhist[bbuf[((size_t)seg * NB + b) * CAP + slot] >> 17], 1);
    }
    __syncthreads();
    int hi = min(N, lo + bsz);
    for (int t = threadIdx.x; t < hi - lo; t += FB) cnt[lo + t] = lhist[t];
}

// scan1 also emits dinv (folded k_dinv).
__global__ __launch_bounds__(BS) void k_scan1(const int* __restrict__ cnt, int* __restrict__ bsum,
                                              float* __restrict__ dinv, int N) {
    __shared__ int s[BS];
    int i = blockIdx.x * BS + threadIdx.x;
    int v = (i < N) ? cnt[i] : 0;
    if (i < N) dinv[i] = rsqrtf((float)(v + 1));   // +1 = self-loop
    s[threadIdx.x] = v;
    __syncthreads();
    for (int off = BS / 2; off > 0; off >>= 1) {
        if (threadIdx.x < off) s[threadIdx.x] += s[threadIdx.x + off];
        __syncthreads();
    }
    if (threadIdx.x == 0) bsum[blockIdx.x] = s[0];
}

__global__ __launch_bounds__(512) void k_scan2(int* bsum, int nb) {
    __shared__ int s[512];
    int t = threadIdx.x;
    int v = (t < nb) ? bsum[t] : 0;
    s[t] = v;
    __syncthreads();
    for (int off = 1; off < 512; off <<= 1) {
        int u = (t >= off) ? s[t - off] : 0;
        __syncthreads();
        s[t] += u;
        __syncthreads();
    }
    if (t < nb) bsum[t] = s[t] - v;   // exclusive of self
}

__global__ __launch_bounds__(BS) void k_scan3(const int* __restrict__ cnt, const int* __restrict__ boff,
                                              int* __restrict__ row_ptr, int N) {
    __shared__ int s[BS];
    int t = threadIdx.x;
    int i = blockIdx.x * BS + t;
    int v = (i < N) ? cnt[i] : 0;
    s[t] = v;
    __syncthreads();
    for (int off = 1; off < BS; off <<= 1) {
        int u = (t >= off) ? s[t - off] : 0;
        __syncthreads();
        s[t] += u;
        __syncthreads();
    }
    int base = boff[blockIdx.x];
    if (i < N) row_ptr[i] = base + s[t] - v;
    if (i == N - 1) row_ptr[N] = base + s[t];
}

// Phase 3: counting-sort into LDS, stream out coalesced.
__global__ __launch_bounds__(FB) void k_fill2(const unsigned* __restrict__ bbuf, const int* __restrict__ bcounts,
                                              const int* __restrict__ row_ptr, const float* __restrict__ dinv,
                                              uint2* __restrict__ entries,
                                              int nch, int bsz, int N) {
    __shared__ int cur[512];
    __shared__ float ldinv[512];
    __shared__ unsigned sorted[LCAP];

    int b = blockIdx.x;
    int lo = b * bsz;
    int hi = min(N, lo + bsz);
    int gbase = row_ptr[lo];
    int tot = row_ptr[hi] - gbase;
    for (int t = threadIdx.x; t < hi - lo; t += FB) {
        cur[t] = row_ptr[lo + t] - gbase;
        ldinv[t] = dinv[lo + t];
    }
    __syncthreads();

    int total = nch * CAP;
    for (int idx = threadIdx.x; idx < total; idx += FB) {
        int seg = idx >> 6, slot = idx & 63;              // CAP == 64
        int c = bcounts[seg * NB + b];                    // wave-uniform
        if (slot < c) {
            unsigned u = bbuf[((size_t)seg * NB + b) * CAP + slot];
            int p = atomicAdd(&cur[u >> 17], 1);
            if (p < LCAP) sorted[p] = u;
        }
    }
    __syncthreads();

    for (int t = threadIdx.x; t < tot; t += FB) {
        unsigned u = sorted[t];
        int s = (int)(u & 0x1FFFFu);
        int doff = (int)(u >> 17);
        float w = dinv[s] * ldinv[doff];
        entries[gbase + t] = make_uint2((unsigned)s, __float_as_uint(w));
    }
}

// ---------------- dense transform (standalone; only G1 uses this now) ------
// Thread = (row-quad, 8-col group), cg-major W in LDS (round-5 layout).
// unroll 2 on the k loop: breaks the loop-carried global-load -> FMA
// dependence (round-5 G1: VALUBusy 31%, latency-stalled at unroll 1).
// unroll FULL spilled in round 1 (356 MB scratch) -- keep it at 2.
template<typename TIN, int K, int M, int LDIN, int LDOUT, bool BIAS, bool RELU, typename TOUT>
__global__ __launch_bounds__(BS) void k_gemm(const TIN* __restrict__ H, const float* __restrict__ Wg,
                                             const float* __restrict__ bias, TOUT* __restrict__ out, int N) {
    constexpr int M8 = (M + 7) & ~7;
    constexpr int CG = M8 / 8;
    constexpr int WSTR = K * 8 + 4;             // floats per cg block (bank stagger)
    __shared__ float Wl[CG * WSTR];
    for (int idx = threadIdx.x; idx < CG * WSTR; idx += BS) {
        int cg = idx / WSTR, rem = idx - cg * WSTR;
        int k = rem >> 3, j = rem & 7;
        int m = cg * 8 + j;
        Wl[idx] = (rem < K * 8 && m < M) ? Wg[(size_t)k * M + m] : 0.f;
    }
    __syncthreads();

    int nrq = (N + 3) >> 2;                     // row-quads
    int idx = blockIdx.x * BS + threadIdx.x;
    if (idx >= nrq * CG) return;
    int rq = idx / CG;                          // const divisor -> magic mul
    int cg = idx - rq * CG;
    int c0 = cg * 8;
    int r0 = rq * 4;
    const float* wb = &Wl[cg * WSTR];

    const TIN* h[4];
    #pragma unroll
    for (int r = 0; r < 4; ++r) {
        int rr = r0 + r; rr = (rr < N) ? rr : (N - 1);   // clamp: safe loads
        h[r] = H + (size_t)rr * LDIN;
    }

    float acc[4][8];
    #pragma unroll
    for (int r = 0; r < 4; ++r)
        #pragma unroll
        for (int m = 0; m < 8; ++m) acc[r][m] = 0.f;

    constexpr int K8 = K & ~7;
    #pragma unroll 2
    for (int k = 0; k < K8; k += 8) {
        float p[4][8];
        load8f(h[0] + k, p[0]);
        load8f(h[1] + k, p[1]);
        load8f(h[2] + k, p[2]);
        load8f(h[3] + k, p[3]);
        const float* wl = wb + k * 8;
        #pragma unroll
        for (int j = 0; j < 8; ++j) {
            float4 wa = *(const float4*)(wl + j * 8);
            float4 wc = *(const float4*)(wl + j * 8 + 4);
            const float wv[8] = {wa.x, wa.y, wa.z, wa.w, wc.x, wc.y, wc.z, wc.w};
            #pragma unroll
            for (int r = 0; r < 4; ++r)
                #pragma unroll
                for (int m = 0; m < 8; ++m)
                    acc[r][m] = fmaf(p[r][j], wv[m], acc[r][m]);
        }
    }
    #pragma unroll
    for (int k = K8; k < K; ++k) {
        const float* wl = wb + k * 8;
        float4 wa = *(const float4*)(wl);
        float4 wc = *(const float4*)(wl + 4);
        const float wv[8] = {wa.x, wa.y, wa.z, wa.w, wc.x, wc.y, wc.z, wc.w};
        #pragma unroll
        for (int r = 0; r < 4; ++r) {
            float pv = (float)h[r][k];
            #pragma unroll
            for (int m = 0; m < 8; ++m)
                acc[r][m] = fmaf(pv, wv[m], acc[r][m]);
        }
    }

    #pragma unroll
    for (int r = 0; r < 4; ++r) {
        int rr = r0 + r;
        if (rr >= N) break;
        float v[8];
        #pragma unroll
        for (int m = 0; m < 8; ++m) {
            int c = c0 + m;
            bool in = (c < M);
            float x = in ? acc[r][m] : 0.f;
            if (BIAS && in) x += bias[c];
            if (RELU) x = fmaxf(x, 0.f);
            v[m] = x;
        }
        store8f(out + (size_t)rr * LDOUT + c0, v);
    }
}

// ---------------- standalone aggregation (only A2 uses this now) -----------
template<typename TIN, typename TOUT, int M, int M8, int LDI, int LDO, bool BIAS, bool RELU>
__global__ __launch_bounds__(BS) void k_agg(const TIN* __restrict__ T, TOUT* __restrict__ out,
                                            const int* __restrict__ row_ptr, const uint2* __restrict__ entries,
                                            const float* __restrict__ dinv, const float* __restrict__ bias,
                                            int N) {
    constexpr int CG = M8 / 8;
    int idx = blockIdx.x * BS + threadIdx.x;
    if (idx >= N * CG) return;
    int i  = idx / CG;                // const divisor -> magic mul
    int cg = idx - i * CG;
    int c0 = cg * 8;

    float di = dinv[i];
    float w0 = di * di;
    float t0[8];
    load8f(T + (size_t)i * LDI + c0, t0);
    float a0[8], a1[8];
    #pragma unroll
    for (int m = 0; m < 8; ++m) { a0[m] = w0 * t0[m]; a1[m] = 0.f; }

    int e0 = row_ptr[i], e1 = row_ptr[i + 1];
    for (int e = e0; e < e1; e += 8) {
        unsigned sidx[8];
        float w[8];
        #pragma unroll
        for (int j = 0; j < 8; ++j) {
            int ee = e + j;
            int ec = (ee < e1) ? ee : (e1 - 1);
            uint2 u = entries[ec];
            sidx[j] = u.x;
            w[j] = (ee < e1) ? __uint_as_float(u.y) : 0.f;
        }
        #pragma unroll
        for (int j = 0; j < 8; ++j) {
            float g[8];
            load8f(T + (size_t)sidx[j] * LDI + c0, g);
            if (j & 1) {
                #pragma unroll
                for (int m = 0; m < 8; ++m) a1[m] = fmaf(w[j], g[m], a1[m]);
            } else {
                #pragma unroll
                for (int m = 0; m < 8; ++m) a0[m] = fmaf(w[j], g[m], a0[m]);
            }
        }
    }

    #pragma unroll
    for (int m = 0; m < 8; ++m) {
        float v = a0[m] + a1[m];
        if (BIAS && (c0 + m) < M) v += bias[c0 + m];
        if (RELU) v = fmaxf(v, 0.f);
        a0[m] = v;
    }
    store8f(out + (size_t)i * LDO + c0, a0);
}

// ---------------- FUSED agg + gemm ----------------
// out = gemm( act(agg(T) [+ab]) , Wg ) [+gb][relu]
// Rationale: aggs are pinned at the random-line wall (164 MB @ ~3.2 TB/s,
// invariant across 34-71% occupancy) with 20% VALU; GEMMs over agg outputs
// are row-local. Fusing the GEMM into the agg block hides its FLOPs (~8%
// extra VALU on a 20%-busy unit) under the same wall and deletes three
// ~50 us standalone GEMMs plus one f16 round-trip each.
// Block: RPB rows. Phase A: (row, 8-col) threads do the gather-agg, result
// rows to LDS in f32. Barrier. Phase B: (row, 8-outcol) threads compute
// row x W from LDS (cg-major W, bank-staggered) and store.
template<typename TIN, typename TOUT,
         int MA, int MA8, int LDI,          // agg width (real/padded) + src ld
         int MG, int MG8, int LDO,          // gemm out width (real/padded) + out ld
         bool ABIAS, bool ARELU, bool GBIAS, bool GRELU>
__global__ __launch_bounds__(BS) void k_agg_gemm(
        const TIN* __restrict__ T, TOUT* __restrict__ out,
        const int* __restrict__ row_ptr, const uint2* __restrict__ entries,
        const float* __restrict__ dinv, const float* __restrict__ Wg,
        const float* __restrict__ ab, const float* __restrict__ gb, int N) {
    constexpr int CGA = MA8 / 8;
    constexpr int RPB = BS / CGA;               // rows per block (28 or 36)
    constexpr int CGG = MG8 / 8;
    constexpr int K = MA;                       // gemm K = real agg width
    constexpr int WSTR = K * 8 + 4;             // cg-major W stride (bank stagger)

    __shared__ float Wl[CGG * WSTR];
    __shared__ float srow[RPB][MA8];

    for (int idx = threadIdx.x; idx < CGG * WSTR; idx += BS) {
        int cg = idx / WSTR, rem = idx - cg * WSTR;
        int k = rem >> 3, j = rem & 7;
        int m = cg * 8 + j;
        Wl[idx] = (rem < K * 8 && m < MG) ? Wg[(size_t)k * MG + m] : 0.f;
    }

    int t = threadIdx.x;
    int r  = t / CGA;                           // const divisor
    int cg = t - r * CGA;
    int i0 = blockIdx.x * RPB;

    if (r < RPB) {
        int i = i0 + r;
        int c0 = cg * 8;
        if (i < N) {
            float di = dinv[i];
            float w0 = di * di;
            float t0[8];
            load8f(T + (size_t)i * LDI + c0, t0);
            float a0[8], a1[8];
            #pragma unroll
            for (int m = 0; m < 8; ++m) { a0[m] = w0 * t0[m]; a1[m] = 0.f; }

            int e0 = row_ptr[i], e1 = row_ptr[i + 1];
            for (int e = e0; e < e1; e += 8) {
                unsigned sidx[8];
                float w[8];
                #pragma unroll
                for (int j = 0; j < 8; ++j) {
                    int ee = e + j;
                    int ec = (ee < e1) ? ee : (e1 - 1);
                    uint2 u = entries[ec];
                    sidx[j] = u.x;
                    w[j] = (ee < e1) ? __uint_as_float(u.y) : 0.f;
                }
                #pragma unroll
                for (int j = 0; j < 8; ++j) {
                    float g[8];
                    load8f(T + (size_t)sidx[j] * LDI + c0, g);
                    if (j & 1) {
                        #pragma unroll
                        for (int m = 0; m < 8; ++m) a1[m] = fmaf(w[j], g[m], a1[m]);
                    } else {
                        #pragma unroll
                        for (int m = 0; m < 8; ++m) a0[m] = fmaf(w[j], g[m], a0[m]);
                    }
                }
            }
            #pragma unroll
            for (int m = 0; m < 8; ++m) {
                float v = a0[m] + a1[m];
                if (ABIAS && (c0 + m) < MA) v += ab[c0 + m];
                if (ARELU) v = fmaxf(v, 0.f);
                srow[r][c0 + m] = v;
            }
        } else {
            #pragma unroll
            for (int m = 0; m < 8; ++m) srow[r][c0 + m] = 0.f;
        }
    }
    __syncthreads();

    // Phase B: row x W. Lanes with equal orow broadcast srow reads; distinct
    // orows land on distinct banks (MA8%32 in {8,24} -> 8*orow spread).
    for (int ow = t; ow < RPB * CGG; ow += BS) {
        int orow = ow / CGG;                    // const divisor
        int ocg  = ow - orow * CGG;
        int gi = i0 + orow;
        if (gi >= N) continue;
        const float* hrow = srow[orow];
        const float* wb = &Wl[ocg * WSTR];
        float acc[8];
        #pragma unroll
        for (int m = 0; m < 8; ++m) acc[m] = 0.f;

        constexpr int K4 = K & ~3;
        #pragma unroll 2
        for (int k = 0; k < K4; k += 4) {
            float4 hv = *(const float4*)(hrow + k);
            const float h4[4] = {hv.x, hv.y, hv.z, hv.w};
            #pragma unroll
            for (int j = 0; j < 4; ++j) {
                const float* wl = wb + (k + j) * 8;
                float4 wa = *(const float4*)wl;
                float4 wc = *(const float4*)(wl + 4);
                acc[0] = fmaf(h4[j], wa.x, acc[0]);
                acc[1] = fmaf(h4[j], wa.y, acc[1]);
                acc[2] = fmaf(h4[j], wa.z, acc[2]);
                acc[3] = fmaf(h4[j], wa.w, acc[3]);
                acc[4] = fmaf(h4[j], wc.x, acc[4]);
                acc[5] = fmaf(h4[j], wc.y, acc[5]);
                acc[6] = fmaf(h4[j], wc.z, acc[6]);
                acc[7] = fmaf(h4[j], wc.w, acc[7]);
            }
        }
        #pragma unroll
        for (int k = K4; k < K; ++k) {
            float hvv = hrow[k];
            const float* wl = wb + k * 8;
            float4 wa = *(const float4*)wl;
            float4 wc = *(const float4*)(wl + 4);
            acc[0] = fmaf(hvv, wa.x, acc[0]);
            acc[1] = fmaf(hvv, wa.y, acc[1]);
            acc[2] = fmaf(hvv, wa.z, acc[2]);
            acc[3] = fmaf(hvv, wa.w, acc[3]);
            acc[4] = fmaf(hvv, wc.x, acc[4]);
            acc[5] = fmaf(hvv, wc.y, acc[5]);
            acc[6] = fmaf(hvv, wc.z, acc[6]);
            acc[7] = fmaf(hvv, wc.w, acc[7]);
        }

        float v[8];
        #pragma unroll
        for (int m = 0; m < 8; ++m) {
            int c = ocg * 8 + m;
            bool in = (c < MG);
            float x = in ? acc[m] : 0.f;
            if (GBIAS && in) x += gb[c];
            if (GRELU) x = fmaxf(x, 0.f);
            v[m] = x;
        }
        store8f(out + (size_t)gi * LDO + ocg * 8, v);
    }
}

// ---------------- driver ----------------

extern "C" void kernel_launch(void* const* d_in, const int* in_sizes, int n_in,
                              void* d_out, int out_size, void* d_ws, size_t ws_size,
                              hipStream_t stream) {
    const float* x  = (const float*)d_in[0];
    const float* W1 = (const float*)d_in[1];
    const float* b1 = (const float*)d_in[2];
    const float* W2 = (const float*)d_in[3];
    const float* b2 = (const float*)d_in[4];
    const float* W3 = (const float*)d_in[5];
    const float* b3 = (const float*)d_in[6];
    const float* W4 = (const float*)d_in[7];
    const float* b4 = (const float*)d_in[8];
    const int* edge_index = (const int*)d_in[9];

    const int N = in_sizes[0] / 88;
    const int E = in_sizes[9] / 2;
    const int* src = edge_index;
    const int* dst = edge_index + E;

    const int nch = (E + CHUNK - 1) / CHUNK;            // 391
    const int bsz = (N + NB - 1) / NB;                  // 391 (< 512, 9-bit doff)
    const unsigned long long invB = ((1ull << 40) + bsz - 1) / bsz;

    // Workspace layout (round-4 verified): CSR scratch (bcounts+bbuf) dead
    // after k_fill2 -> h-buffers alias it. Total ~58 MB.
    auto al = [](size_t b) { return (b + 255) & ~(size_t)255; };
    char* p = (char*)d_ws;
    auto carve = [&](size_t bytes) { void* r = p; p += (bytes + 255) & ~(size_t)255; return r; };
    int*   cnt     = (int*)  carve((size_t)N * 4);
    float* dinv    = (float*)carve((size_t)N * 4);
    int*   row_ptr = (int*)  carve((size_t)(N + 1) * 4);
    int*   bsum    = (int*)  carve(4096);
    uint2* entries = (uint2*)carve((size_t)E * 8);

    char* ub = p;                                        // union region base
    int*      bcounts = (int*)ub;
    unsigned* bbuf    = (unsigned*)(ub + al((size_t)nch * NB * 4));
    size_t csr_bytes  = al((size_t)nch * NB * 4) + al((size_t)nch * NB * CAP * 4);

    size_t hbytes = al((size_t)N * 72 * 2);
    _Float16* hA = (_Float16*)ub;                        // aliases bcounts/bbuf
    _Float16* hC = (_Float16*)(ub + hbytes);
    _Float16* hD = (_Float16*)(ub + 2 * hbytes);
    size_t h_bytes_tot = 3 * hbytes;

    p = ub + (csr_bytes > h_bytes_tot ? csr_bytes : h_bytes_tot);
    (void)p; (void)ws_size;

    int gN = (N + BS - 1) / BS;

    k_bucket<<<nch, BS, 0, stream>>>(src, dst, bbuf, bcounts, E, invB, bsz);
    k_cnt   <<<NB, FB, 0, stream>>>(bbuf, bcounts, cnt, nch, bsz, N);
    k_scan1 <<<gN, BS, 0, stream>>>(cnt, bsum, dinv, N);
    k_scan2 <<<1, 512, 0, stream>>>(bsum, gN);
    k_scan3 <<<gN, BS, 0, stream>>>(cnt, bsum, row_ptr, N);
    k_fill2 <<<NB, FB, 0, stream>>>(bbuf, bcounts, row_ptr, dinv, entries, nch, bsz, N);
    // --- bcounts/bbuf dead from here; hA/hC/hD reuse their storage ---

    auto agg_grid  = [&](int CG) { return (N * CG + BS - 1) / BS; };
    auto gemm_grid = [&](int M)  { int M8 = (M + 7) & ~7; int CG = M8 / 8;
                                   return (((N + 3) / 4) * CG + BS - 1) / BS; };
    const int RPB9 = BS / 9;    // 28 rows/block (agg width 72)
    const int RPB7 = BS / 7;    // 36 rows/block (agg width 56)

    // G1: x(f32, ld88) @ W1 -> hA(f16, ld72)
    k_gemm<float, 88, 65, 88, 72, false, false, _Float16>
        <<<gemm_grid(65), BS, 0, stream>>>(x, W1, nullptr, hA, N);
    // F1 = A1+G2: relu(agg(hA)+b1) @ W2 -> hC(f16, ld56)
    k_agg_gemm<_Float16, _Float16, 65, 72, 72, 50, 56, 56, true, true, false, false>
        <<<(N + RPB9 - 1) / RPB9, BS, 0, stream>>>(hA, hC, row_ptr, entries, dinv, W2, b1, nullptr, N);
    // A2: agg(hC) +b2 -> hD(f16, ld56)
    k_agg<_Float16, _Float16, 50, 56, 56, 56, true, false>
        <<<agg_grid(7), BS, 0, stream>>>(hC, hD, row_ptr, entries, dinv, b2, N);
    // F2 = A3+G3: agg(hD) @ W3 +b3 +relu -> hA(f16, ld72)  [hA dead after F1]
    k_agg_gemm<_Float16, _Float16, 50, 56, 56, 65, 72, 72, false, false, true, true>
        <<<(N + RPB7 - 1) / RPB7, BS, 0, stream>>>(hD, hA, row_ptr, entries, dinv, W3, nullptr, b3, N);
    // F3 = A4+G4: agg(hA) @ W4 +b4 -> d_out(f32, ld88)
    k_agg_gemm<_Float16, float, 65, 72, 72, 88, 88, 88, false, false, true, false>
        <<<(N + RPB9 - 1) / RPB9, BS, 0, stream>>>(hA, (float*)d_out, row_ptr, entries, dinv, W4, nullptr, b4, N);
}

// Round 7
// 425.274 us; speedup vs baseline: 1.9053x; 1.0567x over previous
//
#include <hip/hip_runtime.h>

#define BS 256
#define FB 1024         // threads for bucket-parallel phases
#define NB 256          // dst-range buckets (one block each in phases 2/3)
#define CHUNK 4096      // edges per phase-1 block
#define CAP 64          // slots per (chunk,bucket); Poisson(16), +12 sigma
#define LCAP 8192       // entries per bucket in LDS; Poisson(6250), +24 sigma
#define GRID_F 1024     // persistent-ish grid for fused agg+gemm (4 blocks/CU)

using half8 = __attribute__((ext_vector_type(8))) _Float16;

// 16B row I/O: intermediate layouts padded to 16B rows (ld72 for 65-col,
// ld56 for 50-col). 8 cols per lane everywhere.
template<typename T>
__device__ __forceinline__ void load8f(const T* p, float (&d)[8]) {
    if constexpr (sizeof(T) == 4) {
        float4 a = *(const float4*)p;
        float4 b = *(const float4*)(p + 4);
        d[0] = a.x; d[1] = a.y; d[2] = a.z; d[3] = a.w;
        d[4] = b.x; d[5] = b.y; d[6] = b.z; d[7] = b.w;
    } else {
        half8 v = *(const half8*)p;
        #pragma unroll
        for (int j = 0; j < 8; ++j) d[j] = (float)v[j];
    }
}
template<typename T>
__device__ __forceinline__ void store8f(T* p, const float (&d)[8]) {
    if constexpr (sizeof(T) == 4) {
        *(float4*)p       = make_float4(d[0], d[1], d[2], d[3]);
        *(float4*)(p + 4) = make_float4(d[4], d[5], d[6], d[7]);
    } else {
        half8 h;
        #pragma unroll
        for (int j = 0; j < 8; ++j) h[j] = (_Float16)d[j];
        *(half8*)p = h;
    }
}

// ---------------- CSR build ----------------

// k_bucket_g1: bucket blocks (blockIdx < nch) bucket edges; the remaining
// blocks run G1 (x @ W1 -> hA). The two are data-independent, so G1's ~40 us
// hides under the CSR chain head instead of serializing after it.
// NOTE: hA must NOT alias bbuf/bcounts (G1 writes concurrently with bucket).
__global__ __launch_bounds__(BS) void k_bucket_g1(
        const int* __restrict__ src, const int* __restrict__ dst,
        unsigned* __restrict__ bbuf, int* __restrict__ bcounts,
        int E, unsigned long long invB, int bsz, int nch,
        const float* __restrict__ x, const float* __restrict__ W1,
        _Float16* __restrict__ hA, int N) {
    constexpr int K = 88, M = 65, LDIN = 88, LDOUT = 72;
    constexpr int CG = 9;                      // 72/8
    constexpr int WSTR = K * 8 + 4;            // 708 floats, bank stagger
    __shared__ float sh[CG * WSTR];            // 25.5 KB (bucket aliases as int*)

    if ((int)blockIdx.x < nch) {
        // ---- bucket body ----
        int* lcnt = (int*)sh;
        for (int t = threadIdx.x; t < NB; t += BS) lcnt[t] = 0;
        __syncthreads();
        int base_e = blockIdx.x * CHUNK;
        unsigned* mybuf = bbuf + (size_t)blockIdx.x * NB * CAP;
        #pragma unroll
        for (int j = 0; j < CHUNK / BS; ++j) {
            int e = base_e + j * BS + threadIdx.x;
            if (e < E) {
                int d = dst[e];
                int s = src[e];
                int b = (int)(((unsigned long long)(unsigned)d * invB) >> 40);
                int doff = d - b * bsz;                   // < 512 (9 bits)
                int pos = atomicAdd(&lcnt[b], 1);
                if (pos < CAP)
                    mybuf[b * CAP + pos] = ((unsigned)doff << 17) | (unsigned)s;
            }
        }
        __syncthreads();
        for (int t = threadIdx.x; t < NB; t += BS)
            bcounts[blockIdx.x * NB + t] = min(lcnt[t], CAP);
        return;
    }

    // ---- G1 body: thread = (row-quad, 8-col group), cg-major W ----
    float* Wl = sh;
    for (int idx = threadIdx.x; idx < CG * WSTR; idx += BS) {
        int cg = idx / WSTR, rem = idx - cg * WSTR;
        int k = rem >> 3, j = rem & 7;
        int m = cg * 8 + j;
        Wl[idx] = (rem < K * 8 && m < M) ? W1[(size_t)k * M + m] : 0.f;
    }
    __syncthreads();

    int bid = blockIdx.x - nch;
    int nrq = (N + 3) >> 2;
    int idx = bid * BS + threadIdx.x;
    if (idx >= nrq * CG) return;
    int rq = idx / CG;
    int cg = idx - rq * CG;
    int c0 = cg * 8;
    int r0 = rq * 4;
    const float* wb = &Wl[cg * WSTR];

    const float* h[4];
    #pragma unroll
    for (int r = 0; r < 4; ++r) {
        int rr = r0 + r; rr = (rr < N) ? rr : (N - 1);
        h[r] = x + (size_t)rr * LDIN;
    }
    float acc[4][8];
    #pragma unroll
    for (int r = 0; r < 4; ++r)
        #pragma unroll
        for (int m = 0; m < 8; ++m) acc[r][m] = 0.f;

    #pragma unroll 2
    for (int k = 0; k < K; k += 8) {           // K=88 divisible by 8
        float p[4][8];
        load8f(h[0] + k, p[0]);
        load8f(h[1] + k, p[1]);
        load8f(h[2] + k, p[2]);
        load8f(h[3] + k, p[3]);
        const float* wl = wb + k * 8;
        #pragma unroll
        for (int j = 0; j < 8; ++j) {
            float4 wa = *(const float4*)(wl + j * 8);
            float4 wc = *(const float4*)(wl + j * 8 + 4);
            const float wv[8] = {wa.x, wa.y, wa.z, wa.w, wc.x, wc.y, wc.z, wc.w};
            #pragma unroll
            for (int r = 0; r < 4; ++r)
                #pragma unroll
                for (int m = 0; m < 8; ++m)
                    acc[r][m] = fmaf(p[r][j], wv[m], acc[r][m]);
        }
    }
    #pragma unroll
    for (int r = 0; r < 4; ++r) {
        int rr = r0 + r;
        if (rr >= N) break;
        float v[8];
        #pragma unroll
        for (int m = 0; m < 8; ++m) {
            int c = c0 + m;
            v[m] = (c < M) ? acc[r][m] : 0.f;  // no bias/relu on G1
        }
        store8f(hA + (size_t)rr * LDOUT + c0, v);
    }
}

// Phase 2: per-bucket degree counts. Fully overwrites cnt[0..N).
__global__ __launch_bounds__(FB) void k_cnt(const unsigned* __restrict__ bbuf, const int* __restrict__ bcounts,
                                            int* __restrict__ cnt, int nch, int bsz, int N) {
    __shared__ int lhist[512];
    for (int t = threadIdx.x; t < 512; t += FB) lhist[t] = 0;
    __syncthreads();
    int b = blockIdx.x;
    int lo = b * bsz;
    int total = nch * CAP;
    for (int idx = threadIdx.x; idx < total; idx += FB) {
        int seg = idx >> 6, slot = idx & 63;              // CAP == 64
        int c = bcounts[seg * NB + b];                    // wave-uniform
        if (slot < c)
            atomicAdd(&lhist[bbuf[((size_t)seg * NB + b) * CAP + slot] >> 17], 1);
    }
    __syncthreads();
    int hi = min(N, lo + bsz);
    for (int t = threadIdx.x; t < hi - lo; t += FB) cnt[lo + t] = lhist[t];
}

// scan1 also emits dinv (folded k_dinv).
__global__ __launch_bounds__(BS) void k_scan1(const int* __restrict__ cnt, int* __restrict__ bsum,
                                              float* __restrict__ dinv, int N) {
    __shared__ int s[BS];
    int i = blockIdx.x * BS + threadIdx.x;
    int v = (i < N) ? cnt[i] : 0;
    if (i < N) dinv[i] = rsqrtf((float)(v + 1));   // +1 = self-loop
    s[threadIdx.x] = v;
    __syncthreads();
    for (int off = BS / 2; off > 0; off >>= 1) {
        if (threadIdx.x < off) s[threadIdx.x] += s[threadIdx.x + off];
        __syncthreads();
    }
    if (threadIdx.x == 0) bsum[blockIdx.x] = s[0];
}

__global__ __launch_bounds__(512) void k_scan2(int* bsum, int nb) {
    __shared__ int s[512];
    int t = threadIdx.x;
    int v = (t < nb) ? bsum[t] : 0;
    s[t] = v;
    __syncthreads();
    for (int off = 1; off < 512; off <<= 1) {
        int u = (t >= off) ? s[t - off] : 0;
        __syncthreads();
        s[t] += u;
        __syncthreads();
    }
    if (t < nb) bsum[t] = s[t] - v;   // exclusive of self
}

__global__ __launch_bounds__(BS) void k_scan3(const int* __restrict__ cnt, const int* __restrict__ boff,
                                              int* __restrict__ row_ptr, int N) {
    __shared__ int s[BS];
    int t = threadIdx.x;
    int i = blockIdx.x * BS + t;
    int v = (i < N) ? cnt[i] : 0;
    s[t] = v;
    __syncthreads();
    for (int off = 1; off < BS; off <<= 1) {
        int u = (t >= off) ? s[t - off] : 0;
        __syncthreads();
        s[t] += u;
        __syncthreads();
    }
    int base = boff[blockIdx.x];
    if (i < N) row_ptr[i] = base + s[t] - v;
    if (i == N - 1) row_ptr[N] = base + s[t];
}

// Phase 3: counting-sort into LDS, stream out coalesced.
__global__ __launch_bounds__(FB) void k_fill2(const unsigned* __restrict__ bbuf, const int* __restrict__ bcounts,
                                              const int* __restrict__ row_ptr, const float* __restrict__ dinv,
                                              uint2* __restrict__ entries,
                                              int nch, int bsz, int N) {
    __shared__ int cur[512];
    __shared__ float ldinv[512];
    __shared__ unsigned sorted[LCAP];

    int b = blockIdx.x;
    int lo = b * bsz;
    int hi = min(N, lo + bsz);
    int gbase = row_ptr[lo];
    int tot = row_ptr[hi] - gbase;
    for (int t = threadIdx.x; t < hi - lo; t += FB) {
        cur[t] = row_ptr[lo + t] - gbase;
        ldinv[t] = dinv[lo + t];
    }
    __syncthreads();

    int total = nch * CAP;
    for (int idx = threadIdx.x; idx < total; idx += FB) {
        int seg = idx >> 6, slot = idx & 63;              // CAP == 64
        int c = bcounts[seg * NB + b];                    // wave-uniform
        if (slot < c) {
            unsigned u = bbuf[((size_t)seg * NB + b) * CAP + slot];
            int p = atomicAdd(&cur[u >> 17], 1);
            if (p < LCAP) sorted[p] = u;
        }
    }
    __syncthreads();

    for (int t = threadIdx.x; t < tot; t += FB) {
        unsigned u = sorted[t];
        int s = (int)(u & 0x1FFFFu);
        int doff = (int)(u >> 17);
        float w = dinv[s] * ldinv[doff];
        entries[gbase + t] = make_uint2((unsigned)s, __float_as_uint(w));
    }
}

// ---------------- standalone aggregation (only A2 uses this) -----------
template<typename TIN, typename TOUT, int M, int M8, int LDI, int LDO, bool BIAS, bool RELU>
__global__ __launch_bounds__(BS) void k_agg(const TIN* __restrict__ T, TOUT* __restrict__ out,
                                            const int* __restrict__ row_ptr, const uint2* __restrict__ entries,
                                            const float* __restrict__ dinv, const float* __restrict__ bias,
                                            int N) {
    constexpr int CG = M8 / 8;
    int idx = blockIdx.x * BS + threadIdx.x;
    if (idx >= N * CG) return;
    int i  = idx / CG;                // const divisor -> magic mul
    int cg = idx - i * CG;
    int c0 = cg * 8;

    float di = dinv[i];
    float w0 = di * di;
    float t0[8];
    load8f(T + (size_t)i * LDI + c0, t0);
    float a0[8], a1[8];
    #pragma unroll
    for (int m = 0; m < 8; ++m) { a0[m] = w0 * t0[m]; a1[m] = 0.f; }

    int e0 = row_ptr[i], e1 = row_ptr[i + 1];
    for (int e = e0; e < e1; e += 8) {
        unsigned sidx[8];
        float w[8];
        #pragma unroll
        for (int j = 0; j < 8; ++j) {
            int ee = e + j;
            int ec = (ee < e1) ? ee : (e1 - 1);
            uint2 u = entries[ec];
            sidx[j] = u.x;
            w[j] = (ee < e1) ? __uint_as_float(u.y) : 0.f;
        }
        #pragma unroll
        for (int j = 0; j < 8; ++j) {
            float g[8];
            load8f(T + (size_t)sidx[j] * LDI + c0, g);
            if (j & 1) {
                #pragma unroll
                for (int m = 0; m < 8; ++m) a1[m] = fmaf(w[j], g[m], a1[m]);
            } else {
                #pragma unroll
                for (int m = 0; m < 8; ++m) a0[m] = fmaf(w[j], g[m], a0[m]);
            }
        }
    }

    #pragma unroll
    for (int m = 0; m < 8; ++m) {
        float v = a0[m] + a1[m];
        if (BIAS && (c0 + m) < M) v += bias[c0 + m];
        if (RELU) v = fmaxf(v, 0.f);
        a0[m] = v;
    }
    store8f(out + (size_t)i * LDO + c0, a0);
}

// ---------------- FUSED agg + gemm, software-pipelined ----------------
// out = gemm( act(agg(T) [+ab]) , Wg ) [+gb][relu]
// Round-6 lesson: A-phase/barrier/B-phase serializes gather demand (rate fell
// 2.9 -> 1.77 TB/s). This version pipelines tiles: stage s gathers tile t+1
// while computing the GEMM of tile t -- and the GEMM chunk (LDS/VALU only) is
// placed BETWEEN the gather-load issue and the gather consume, so the global
// loads stay in flight under the FMAs (in-order wave => perfect overlap).
// RPB chosen so RPB*CGA <= 256 and RPB*CGG <= 256 (single-pass phases; the
// round-6 2-pass phase B wasted half its time at 20% utilization).
template<typename TIN, typename TOUT,
         int MA, int MA8, int LDI,          // agg width (real/padded) + src ld
         int MG, int MG8, int LDO,          // gemm out width (real/padded) + out ld
         int RPB,                           // rows per tile
         bool ABIAS, bool ARELU, bool GBIAS, bool GRELU>
__global__ __launch_bounds__(BS) void k_agg_gemm(
        const TIN* __restrict__ T, TOUT* __restrict__ out,
        const int* __restrict__ row_ptr, const uint2* __restrict__ entries,
        const float* __restrict__ dinv, const float* __restrict__ Wg,
        const float* __restrict__ ab, const float* __restrict__ gb, int N) {
    constexpr int CGA = MA8 / 8;
    constexpr int CGG = MG8 / 8;
    constexpr int K = MA;                       // gemm K = real agg width
    constexpr int WSTR = K * 8 + 4;             // cg-major W stride (bank stagger)
    constexpr int BC = 32;                      // gemm k-steps per gather batch

    __shared__ float Wl[CGG * WSTR];
    __shared__ float srow[2][RPB][MA8];

    for (int idx = threadIdx.x; idx < CGG * WSTR; idx += BS) {
        int cg = idx / WSTR, rem = idx - cg * WSTR;
        int k = rem >> 3, j = rem & 7;
        int m = cg * 8 + j;
        Wl[idx] = (rem < K * 8 && m < MG) ? Wg[(size_t)k * MG + m] : 0.f;
    }

    const int t = threadIdx.x;
    const int rA = t / CGA, cgA = t - rA * CGA, c0A = cgA * 8;
    const bool hasA = (rA < RPB);
    const int rB = t / CGG, cgB = t - rB * CGG, c0B = cgB * 8;
    const bool hasB = (rB < RPB);
    const float* wbB = &Wl[cgB * WSTR];
    const int ntiles = (N + RPB - 1) / RPB;

    for (int s = 0; ; ++s) {
        int tA = (int)blockIdx.x + s * (int)gridDim.x;          // tile to gather
        int tB = (int)blockIdx.x + (s - 1) * (int)gridDim.x;    // tile to gemm
        bool anyA = (tA < ntiles);
        bool anyB = (s >= 1) && (tB < ntiles);
        if (!anyA && !anyB) break;
        int bufA = s & 1, bufB = bufA ^ 1;

        int iA = tA * RPB + rA;
        bool doA = anyA && hasA && (iA < N);
        int iB = tB * RPB + rB;
        bool doB = anyB && hasB && (iB < N);

        float bacc[8];
        #pragma unroll
        for (int m = 0; m < 8; ++m) bacc[m] = 0.f;
        int bk = 0;
        const float* hrow = &srow[bufB][hasB ? rB : 0][0];

        if (doA) {
            float di = dinv[iA];
            float w0 = di * di;
            float t0[8];
            load8f(T + (size_t)iA * LDI + c0A, t0);
            float a0[8], a1[8];
            #pragma unroll
            for (int m = 0; m < 8; ++m) { a0[m] = w0 * t0[m]; a1[m] = 0.f; }

            int e0 = row_ptr[iA], e1 = row_ptr[iA + 1];
            for (int e = e0; e < e1; e += 8) {
                unsigned sidx[8];
                float w[8];
                #pragma unroll
                for (int j = 0; j < 8; ++j) {
                    int ee = e + j;
                    int ec = (ee < e1) ? ee : (e1 - 1);
                    uint2 u = entries[ec];
                    sidx[j] = u.x;
                    w[j] = (ee < e1) ? __uint_as_float(u.y) : 0.f;
                }
                // issue all 8 row gathers (stay in flight under the B chunk)
                float g[8][8];
                #pragma unroll
                for (int j = 0; j < 8; ++j)
                    load8f(T + (size_t)sidx[j] * LDI + c0A, g[j]);
                // B chunk: LDS + VALU only, no use of g -> no waitcnt before it
                if (doB) {
                    int lim = bk + BC; if (lim > K) lim = K;
                    for (; bk < lim; ++bk) {
                        float hv = hrow[bk];
                        const float* wl = wbB + bk * 8;
                        float4 wa = *(const float4*)wl;
                        float4 wc = *(const float4*)(wl + 4);
                        bacc[0] = fmaf(hv, wa.x, bacc[0]);
                        bacc[1] = fmaf(hv, wa.y, bacc[1]);
                        bacc[2] = fmaf(hv, wa.z, bacc[2]);
                        bacc[3] = fmaf(hv, wa.w, bacc[3]);
                        bacc[4] = fmaf(hv, wc.x, bacc[4]);
                        bacc[5] = fmaf(hv, wc.y, bacc[5]);
                        bacc[6] = fmaf(hv, wc.z, bacc[6]);
                        bacc[7] = fmaf(hv, wc.w, bacc[7]);
                    }
                }
                // consume gathers
                #pragma unroll
                for (int j = 0; j < 8; ++j) {
                    if (j & 1) {
                        #pragma unroll
                        for (int m = 0; m < 8; ++m) a1[m] = fmaf(w[j], g[j][m], a1[m]);
                    } else {
                        #pragma unroll
                        for (int m = 0; m < 8; ++m) a0[m] = fmaf(w[j], g[j][m], a0[m]);
                    }
                }
            }
            #pragma unroll
            for (int m = 0; m < 8; ++m) {
                float v = a0[m] + a1[m];
                if (ABIAS && (c0A + m) < MA) v += ab[c0A + m];
                if (ARELU) v = fmaxf(v, 0.f);
                srow[bufA][rA][c0A + m] = v;
            }
        }
        // B drain + epilogue store
        if (doB) {
            for (; bk < K; ++bk) {
                float hv = hrow[bk];
                const float* wl = wbB + bk * 8;
                float4 wa = *(const float4*)wl;
                float4 wc = *(const float4*)(wl + 4);
                bacc[0] = fmaf(hv, wa.x, bacc[0]);
                bacc[1] = fmaf(hv, wa.y, bacc[1]);
                bacc[2] = fmaf(hv, wa.z, bacc[2]);
                bacc[3] = fmaf(hv, wa.w, bacc[3]);
                bacc[4] = fmaf(hv, wc.x, bacc[4]);
                bacc[5] = fmaf(hv, wc.y, bacc[5]);
                bacc[6] = fmaf(hv, wc.z, bacc[6]);
                bacc[7] = fmaf(hv, wc.w, bacc[7]);
            }
            float v[8];
            #pragma unroll
            for (int m = 0; m < 8; ++m) {
                int c = c0B + m;
                bool in = (c < MG);
                float xv = in ? bacc[m] : 0.f;
                if (GBIAS && in) xv += gb[c];
                if (GRELU) xv = fmaxf(xv, 0.f);
                v[m] = xv;
            }
            store8f(out + (size_t)iB * LDO + c0B, v);
        }
        __syncthreads();   // srow[bufA] complete; safe for next stage's B / overwrite
    }
}

// ---------------- driver ----------------

extern "C" void kernel_launch(void* const* d_in, const int* in_sizes, int n_in,
                              void* d_out, int out_size, void* d_ws, size_t ws_size,
                              hipStream_t stream) {
    const float* x  = (const float*)d_in[0];
    const float* W1 = (const float*)d_in[1];
    const float* b1 = (const float*)d_in[2];
    const float* W2 = (const float*)d_in[3];
    const float* b2 = (const float*)d_in[4];
    const float* W3 = (const float*)d_in[5];
    const float* b3 = (const float*)d_in[6];
    const float* W4 = (const float*)d_in[7];
    const float* b4 = (const float*)d_in[8];
    const int* edge_index = (const int*)d_in[9];

    const int N = in_sizes[0] / 88;
    const int E = in_sizes[9] / 2;
    const int* src = edge_index;
    const int* dst = edge_index + E;

    const int nch = (E + CHUNK - 1) / CHUNK;            // 391
    const int bsz = (N + NB - 1) / NB;                  // 391 (< 512, 9-bit doff)
    const unsigned long long invB = ((1ull << 40) + bsz - 1) / bsz;

    // Workspace: hA is now OUTSIDE the union (G1 writes it concurrently with
    // k_bucket's bbuf writes in the merged launch). Only hC/hD alias the CSR
    // scratch (first written after k_fill2). Total ~57 MB (round-2-safe).
    auto al = [](size_t b) { return (b + 255) & ~(size_t)255; };
    char* p = (char*)d_ws;
    auto carve = [&](size_t bytes) { void* r = p; p += (bytes + 255) & ~(size_t)255; return r; };
    int*   cnt     = (int*)  carve((size_t)N * 4);
    float* dinv    = (float*)carve((size_t)N * 4);
    int*   row_ptr = (int*)  carve((size_t)(N + 1) * 4);
    int*   bsum    = (int*)  carve(4096);
    uint2* entries = (uint2*)carve((size_t)E * 8);
    _Float16* hA   = (_Float16*)carve((size_t)N * 72 * 2);   // NOT aliased

    char* ub = p;                                        // union region base
    int*      bcounts = (int*)ub;
    unsigned* bbuf    = (unsigned*)(ub + al((size_t)nch * NB * 4));
    size_t csr_bytes  = al((size_t)nch * NB * 4) + al((size_t)nch * NB * CAP * 4);

    size_t hbytes = al((size_t)N * 72 * 2);
    _Float16* hC = (_Float16*)ub;                        // aliases bcounts/bbuf
    _Float16* hD = (_Float16*)(ub + hbytes);
    size_t h_bytes_tot = 2 * hbytes;

    p = ub + (csr_bytes > h_bytes_tot ? csr_bytes : h_bytes_tot);
    (void)p; (void)ws_size;

    int gN = (N + BS - 1) / BS;
    int g1b = (((N + 3) / 4) * 9 + BS - 1) / BS;         // G1 blocks (row-quads x 9 cg)

    // CSR build + G1 overlapped in one launch.
    k_bucket_g1<<<nch + g1b, BS, 0, stream>>>(src, dst, bbuf, bcounts, E, invB, bsz, nch,
                                              x, W1, hA, N);
    k_cnt   <<<NB, FB, 0, stream>>>(bbuf, bcounts, cnt, nch, bsz, N);
    k_scan1 <<<gN, BS, 0, stream>>>(cnt, bsum, dinv, N);
    k_scan2 <<<1, 512, 0, stream>>>(bsum, gN);
    k_scan3 <<<gN, BS, 0, stream>>>(cnt, bsum, row_ptr, N);
    k_fill2 <<<NB, FB, 0, stream>>>(bbuf, bcounts, row_ptr, dinv, entries, nch, bsz, N);
    // --- bcounts/bbuf dead from here; hC/hD reuse their storage ---

    auto agg_grid = [&](int CG) { return (N * CG + BS - 1) / BS; };

    // F1 = A1+G2: relu(agg(hA)+b1) @ W2 -> hC(f16, ld56)   [RPB 28: A 252, B 196]
    k_agg_gemm<_Float16, _Float16, 65, 72, 72, 50, 56, 56, 28, true, true, false, false>
        <<<GRID_F, BS, 0, stream>>>(hA, hC, row_ptr, entries, dinv, W2, b1, nullptr, N);
    // A2: agg(hC) +b2 -> hD(f16, ld56)
    k_agg<_Float16, _Float16, 50, 56, 56, 56, true, false>
        <<<agg_grid(7), BS, 0, stream>>>(hC, hD, row_ptr, entries, dinv, b2, N);
    // F2 = A3+G3: agg(hD) @ W3 +b3 +relu -> hA(f16, ld72)  [RPB 28: A 196, B 252]
    k_agg_gemm<_Float16, _Float16, 50, 56, 56, 65, 72, 72, 28, false, false, true, true>
        <<<GRID_F, BS, 0, stream>>>(hD, hA, row_ptr, entries, dinv, W3, nullptr, b3, N);
    // F3 = A4+G4: agg(hA) @ W4 +b4 -> d_out(f32, ld88)     [RPB 23: A 207, B 253]
    k_agg_gemm<_Float16, float, 65, 72, 72, 88, 88, 88, 23, false, false, true, false>
        <<<GRID_F, BS, 0, stream>>>(hA, (float*)d_out, row_ptr, entries, dinv, W4, nullptr, b4, N);
}